// Round 4
// baseline (695.116 us; speedup 1.0000x reference)
//
#include <hip/hip_runtime.h>
#include <hip/hip_bf16.h>

// Problem constants
#define BATCH   2048
#define HW      81          // 9x9
#define CIN     39
#define NPIX    (BATCH*HW)  // 165888

// ws layout (float offsets)
#define WS_H1     0              // 10,616,832 floats  (B,64,81)  PRE-BN h
#define WS_MASK   10616832       // 1,492,992 floats   (B,9,81)
#define WS_WDT    12109824       // 36,864 ushort bf16 [k][o][c]   (18,432 floats)
#define WS_W1M    12128256       // 24,576 ushort bf16 [12][64][32] (12,288 floats)
#define WS_WCM    12140544       // 18,432 ushort bf16 [18][32][32] (9,216 floats)
#define WS_STATS  12149760       // 512 floats: sum1,sq1,sum2,sq2,scale1,shift1,scale2,shift2

#define OUT_OFF_BASE 1
#define OUT_H_BASE   (1 + BATCH*18*81)   // 2985985

typedef __attribute__((ext_vector_type(8))) short bfrag8;
typedef __attribute__((ext_vector_type(4))) float floatx4;

__device__ __forceinline__ unsigned short f2bf(float f) {
    unsigned u = __builtin_bit_cast(unsigned, f);
    u += 0x7FFFu + ((u >> 16) & 1u);       // round-to-nearest-even
    return (unsigned short)(u >> 16);
}

// ---------------- weight prep: fragment-ready bf16 layouts --------------------
// w1m: [s(12)][o(64)][kk(32)]  k-map: s<9: (tap=s, c=kk); s=9: (tap=kk>>3, c=32+(kk&7));
//      s=10: (tap=4+(kk>>3), c=32+(kk&7)); s=11: (tap=8, c=32+(kk&7)) for kk<8 else 0.
// wcm: [s(18)][oc(32)][kk(32)] k-map: tap=s>>1, c=(s&1)*32+kk. oc>=27 rows zero.
// wdt: [k(9)][o(64)][c(64)] bf16 (deform)
__global__ void prep_weights(const float* __restrict__ w1, const float* __restrict__ wo,
                             const float* __restrict__ wm, const float* __restrict__ wd,
                             float* __restrict__ ws) {
    int idx = blockIdx.x * 256 + threadIdx.x;
    unsigned short* w1m = (unsigned short*)(ws + WS_W1M);
    unsigned short* wcm = (unsigned short*)(ws + WS_WCM);
    unsigned short* wdt16 = (unsigned short*)(ws + WS_WDT);
    if (idx < 24576) {
        int kk = idx & 31, o = (idx >> 5) & 63, s = idx >> 11;
        int tap, c; bool ok = true;
        if (s < 9)       { tap = s;             c = kk; }
        else if (s == 9) { tap = kk >> 3;       c = 32 + (kk & 7); }
        else if (s == 10){ tap = 4 + (kk >> 3); c = 32 + (kk & 7); }
        else             { tap = 8;             c = 32 + (kk & 7); ok = (kk < 8); }
        float v = (ok && c < CIN) ? w1[(o * CIN + c) * 9 + tap] : 0.f;
        w1m[idx] = f2bf(v);
        return;
    }
    int j = idx - 24576;
    if (j >= 0 && j < 18432) {
        int kk = j & 31, oc = (j >> 5) & 31, s = j >> 10;
        int tap = s >> 1, c = (s & 1) * 32 + kk;
        float v = 0.f;
        if (oc < 18)      v = wo[(oc * 64 + c) * 9 + tap];
        else if (oc < 27) v = wm[((oc - 18) * 64 + c) * 9 + tap];
        wcm[j] = f2bf(v);
        return;
    }
    int m = idx - 24576 - 18432;
    if (m >= 0 && m < 36864) {
        int c = m & 63, o = (m >> 6) & 63, k = m >> 12;
        wdt16[m] = f2bf(wd[(o * 64 + c) * 9 + k]);
    }
}

// ---------------- conv1 (39->64) MFMA + ReLU + BN1 stats ----------------------
__global__ __launch_bounds__(256) void conv1_mfma(
        const float* __restrict__ xg, const float* __restrict__ b1,
        const unsigned short* __restrict__ w1m, float* __restrict__ h1,
        float* __restrict__ sum1, float* __restrict__ sq1) {
    __shared__ short xs[128 * 64];   // [r(121)][c(64)] bf16, byte ^= (r&7)<<4
    int b = blockIdx.x, t = threadIdx.x;
    for (int i = t; i < 4096; i += 256) ((unsigned*)xs)[i] = 0u;
    __syncthreads();
    const float* xb = xg + (size_t)b * (HW * CIN);
    for (int i = t; i < HW * CIN; i += 256) {
        int p = i / 39, c = i - 39 * p;
        int y = p / 9, xx = p - 9 * y;
        int r = (y + 1) * 11 + xx + 1;
        int byte = r * 128 + ((c * 2) ^ ((r & 7) << 4));
        xs[byte >> 1] = (short)f2bf(xb[i]);
    }
    __syncthreads();
    int lane = t & 63, wv = t >> 6, lg = lane >> 4, lr = lane & 15;
    int o = wv * 16 + lr;
    bfrag8 a[12];
#pragma unroll
    for (int s = 0; s < 12; ++s)
        a[s] = *(const bfrag8*)&w1m[(s * 64 + o) * 32 + lg * 8];
    floatx4 acc[6];
#pragma unroll
    for (int n = 0; n < 6; ++n) acc[n] = (floatx4)0.f;
#pragma unroll
    for (int n = 0; n < 6; ++n) {
        int p = n * 16 + lr; p = p > 80 ? 80 : p;
        int y = p / 9, xx = p - 9 * y;
        int rb = (y + 1) * 11 + xx + 1;
#pragma unroll
        for (int s = 0; s < 12; ++s) {
            int r, cb;
            if (s < 9)       { r = rb + (s / 3 - 1) * 11 + (s % 3) - 1; cb = lg * 16; }
            else if (s == 9) { r = rb + (lg / 3 - 1) * 11 + (lg % 3) - 1; cb = 64; }
            else if (s == 10){ int tp = lg + 4; r = rb + (tp / 3 - 1) * 11 + (tp % 3) - 1; cb = 64; }
            else             { r = rb + 12; cb = 64; }
            int byte = r * 128 + (cb ^ ((r & 7) << 4));
            bfrag8 bf = *(const bfrag8*)((const char*)xs + byte);
            acc[n] = __builtin_amdgcn_mfma_f32_16x16x32_bf16(a[s], bf, acc[n], 0, 0, 0);
        }
    }
    float* h1b = h1 + (size_t)b * 5184;
#pragma unroll
    for (int j = 0; j < 4; ++j) {
        int oo = wv * 16 + lg * 4 + j;
        float bias = b1[oo];
        float ss = 0.f, qq = 0.f;
#pragma unroll
        for (int n = 0; n < 6; ++n) {
            int p = n * 16 + lr;
            float v = fmaxf(acc[n][j] + bias, 0.f);
            if (p < 81) { h1b[oo * 81 + p] = v; ss += v; qq += v * v; }
        }
#pragma unroll
        for (int off = 1; off < 16; off <<= 1) { ss += __shfl_xor(ss, off); qq += __shfl_xor(qq, off); }
        if (lr == 0) { atomicAdd(&sum1[oo], ss); atomicAdd(&sq1[oo], qq); }
    }
}

// ---------------- BN finalize -------------------------------------------------
__global__ void bn_finalize(const float* __restrict__ sums, const float* __restrict__ sqs,
                            const float* __restrict__ gamma, const float* __restrict__ beta,
                            float* __restrict__ scale, float* __restrict__ shift) {
    int t = threadIdx.x;   // 64
    float m = sums[t] / (float)NPIX;
    float v = sqs[t] / (float)NPIX - m * m;
    float sc = gamma[t] * (1.f / sqrtf(v + 1e-5f));
    scale[t] = sc;
    shift[t] = beta[t] - m * sc;
}

// ---------------- BN apply (final output) -------------------------------------
__global__ void bn_apply(float* __restrict__ data, const float* __restrict__ scale,
                         const float* __restrict__ shift, int n, int writeProb,
                         float* __restrict__ dout) {
    int i = blockIdx.x * blockDim.x + threadIdx.x;
    if (writeProb && i == 0) dout[0] = 0.5f;
    for (; i < n; i += gridDim.x * blockDim.x) {
        int c = (i / 81) & 63;
        data[i] = data[i] * scale[c] + shift[c];
    }
}

// ---------------- offset(18) + mask(9, sigmoid) conv, MFMA --------------------
__global__ __launch_bounds__(256) void offmask_mfma(
        const float* __restrict__ h1, const unsigned short* __restrict__ wcm,
        const float* __restrict__ bo, const float* __restrict__ bm,
        const float* __restrict__ scale1, const float* __restrict__ shift1,
        float* __restrict__ dout, float* __restrict__ maskbuf) {
    __shared__ float hsh[5184];
    __shared__ short xs[128 * 64];   // padded swizzled bf16 post-BN image
    __shared__ float sc[64], sh[64];
    int b = blockIdx.x, t = threadIdx.x;
    for (int i = t; i < 4096; i += 256) ((unsigned*)xs)[i] = 0u;
    if (t < 128) { if (t < 64) sc[t] = scale1[t]; else sh[t - 64] = shift1[t - 64]; }
    const float* hb = h1 + (size_t)b * 5184;
    for (int i = t; i < 1296; i += 256) ((float4*)hsh)[i] = ((const float4*)hb)[i];
    __syncthreads();
    for (int i = t; i < 5184; i += 256) {
        int p = i >> 6, c = i & 63;
        float v = hsh[c * 81 + p] * sc[c] + sh[c];
        int y = p / 9, xx = p - 9 * y;
        int r = (y + 1) * 11 + xx + 1;
        int byte = r * 128 + ((c * 2) ^ ((r & 7) << 4));
        xs[byte >> 1] = (short)f2bf(v);
    }
    __syncthreads();
    int lane = t & 63, wv = t >> 6, lg = lane >> 4, lr = lane & 15;
    int mt = wv >> 1, nh = (wv & 1) * 3;
    int ocr = mt * 16 + lr;
    bfrag8 a[18];
#pragma unroll
    for (int s = 0; s < 18; ++s)
        a[s] = *(const bfrag8*)&wcm[(s * 32 + ocr) * 32 + lg * 8];
    floatx4 acc[3];
#pragma unroll
    for (int n = 0; n < 3; ++n) acc[n] = (floatx4)0.f;
#pragma unroll
    for (int ni = 0; ni < 3; ++ni) {
        int p = (nh + ni) * 16 + lr; p = p > 80 ? 80 : p;
        int y = p / 9, xx = p - 9 * y;
        int rb = (y + 1) * 11 + xx + 1;
#pragma unroll
        for (int s = 0; s < 18; ++s) {
            int tap = s >> 1, ch = s & 1;
            int r = rb + (tap / 3 - 1) * 11 + (tap % 3) - 1;
            int byte = r * 128 + ((ch * 64 + lg * 16) ^ ((r & 7) << 4));
            bfrag8 bf = *(const bfrag8*)((const char*)xs + byte);
            acc[ni] = __builtin_amdgcn_mfma_f32_16x16x32_bf16(a[s], bf, acc[ni], 0, 0, 0);
        }
    }
#pragma unroll
    for (int j = 0; j < 4; ++j) {
        int oc = mt * 16 + lg * 4 + j;
        if (oc < 18) {
            float bias = bo[oc];
            float* ob = dout + OUT_OFF_BASE + (size_t)b * 1458 + oc * 81;
#pragma unroll
            for (int ni = 0; ni < 3; ++ni) {
                int p = (nh + ni) * 16 + lr;
                if (p < 81) ob[p] = acc[ni][j] + bias;
            }
        } else if (oc < 27) {
            float bias = bm[oc - 18];
            float* mb = maskbuf + (size_t)b * 729 + (oc - 18) * 81;
#pragma unroll
            for (int ni = 0; ni < 3; ++ni) {
                int p = (nh + ni) * 16 + lr;
                if (p < 81) { float v = acc[ni][j] + bias; mb[p] = 1.f / (1.f + expf(-v)); }
            }
        }
    }
}

// ---------------- deformable conv (MFMA, whole-V single-barrier) ---------------
// V[81 p][576 c=k*64+cc] bf16 in LDS, XOR-swizzled (byte ^= (p&7)<<4 within row).
// A (deform weights) in registers: 18 bfrag8/lane from L2-hot global.
// h staged transposed [p][c] f32 with 8B-preserving XOR so corner reads are
// conflict-free b64 serving 2 channels. 8 waves: (mt = wv>>1) x (nh = (wv&1)*3).
__global__ __launch_bounds__(512, 2) void deform_mfma(
        const float* __restrict__ h1, const unsigned short* __restrict__ wdt16,
        const float* __restrict__ maskbuf, const float* __restrict__ bd,
        const float* __restrict__ scale1, const float* __restrict__ shift1,
        float* __restrict__ dout, float* __restrict__ sum2, float* __restrict__ sq2) {
    __shared__ short    vsh[81 * 576];   // 93312 B
    __shared__ float    hsh[81 * 64];    // 20736 B, byte: p*256 + ((c*4)^((p&31)<<3))
    __shared__ float4   bwtf[729];       // 11664 B  bilinear weights (mask folded)
    __shared__ unsigned bix[729];        // 2916 B   4x u8 corner indices

    int b = blockIdx.x, t = threadIdx.x;
    int lane = t & 63, wv = t >> 6;
    int lg = lane >> 4, lr = lane & 15;
    int mt = wv >> 1, nh = (wv & 1) * 3;

    // ---- A fragments from global (issued early, held in 72 VGPRs)
    bfrag8 a[18];
#pragma unroll
    for (int s = 0; s < 18; ++s) {
        int k = s >> 1, half = s & 1;
        a[s] = *(const bfrag8*)&wdt16[(k * 64 + mt * 16 + lr) * 64 + half * 32 + lg * 8];
    }

    // ---- stage h transposed + swizzled, BN1 folded
    const float* hb = h1 + (size_t)b * 5184;
    for (int i = t; i < 5184; i += 512) {
        int c = i / 81, p = i - c * 81;
        float v = hb[i] * scale1[c] + shift1[c];
        *(float*)((char*)hsh + p * 256 + ((c * 4) ^ ((p & 31) << 3))) = v;
    }

    // ---- bilinear params once per (tap,pixel)
    const float* goff = dout + OUT_OFF_BASE + (size_t)b * 1458;
    const float* gmsk = maskbuf + (size_t)b * 729;
    for (int i = t; i < 729; i += 512) {
        int k = i / 81, p = i - k * 81;
        float dy = goff[(2 * k) * 81 + p];
        float dx = goff[(2 * k + 1) * 81 + p];
        float m  = gmsk[i];
        int y = p / 9, xx = p - y * 9;
        float py = dy + (float)(y + k / 3 - 1);
        float px = dx + (float)(xx + (k % 3) - 1);
        float fy = floorf(py), fx = floorf(px);
        float ly = py - fy, lx = px - fx;
        int y0 = (int)fy, x0 = (int)fx;
        int y1 = y0 + 1, x1 = x0 + 1;
        bool vy0 = (y0 >= 0) & (y0 < 9), vy1 = (y1 >= 0) & (y1 < 9);
        bool vx0 = (x0 >= 0) & (x0 < 9), vx1 = (x1 >= 0) & (x1 < 9);
        float w00 = (vy0 && vx0) ? m * (1.f - ly) * (1.f - lx) : 0.f;
        float w01 = (vy0 && vx1) ? m * (1.f - ly) * lx : 0.f;
        float w10 = (vy1 && vx0) ? m * ly * (1.f - lx) : 0.f;
        float w11 = (vy1 && vx1) ? m * ly * lx : 0.f;
        int yc0 = min(max(y0, 0), 8), yc1 = min(max(y1, 0), 8);
        int xc0 = min(max(x0, 0), 8), xc1 = min(max(x1, 0), 8);
        unsigned i00 = yc0 * 9 + xc0, i01 = yc0 * 9 + xc1;
        unsigned i10 = yc1 * 9 + xc0, i11 = yc1 * 9 + xc1;
        bwtf[i] = make_float4(w00, w01, w10, w11);
        bix[i] = i00 | (i01 << 8) | (i10 << 16) | (i11 << 24);
    }
    __syncthreads();

    // ---- fill whole V: 729 (k,p) x 32 channel-pairs
    for (int i = t; i < 23328; i += 512) {
        int c2 = i & 31, kp = i >> 5;          // lanes 0..31 share kp
        int k = kp / 81, p = kp - 81 * k;
        float4 w = bwtf[kp];
        unsigned ix = bix[kp];
        int i00 = ix & 255, i01 = (ix >> 8) & 255, i10 = (ix >> 16) & 255, i11 = ix >> 24;
        int cb = c2 * 8;
        const char* hc = (const char*)hsh;
        float2 v00 = *(const float2*)(hc + i00 * 256 + (cb ^ ((i00 & 31) << 3)));
        float2 v01 = *(const float2*)(hc + i01 * 256 + (cb ^ ((i01 & 31) << 3)));
        float2 v10 = *(const float2*)(hc + i10 * 256 + (cb ^ ((i10 & 31) << 3)));
        float2 v11 = *(const float2*)(hc + i11 * 256 + (cb ^ ((i11 & 31) << 3)));
        float s0 = w.x * v00.x + w.y * v01.x + w.z * v10.x + w.w * v11.x;
        float s1 = w.x * v00.y + w.y * v01.y + w.z * v10.y + w.w * v11.y;
        *(unsigned*)((char*)vsh + p * 1152 + ((k * 128 + c2 * 4) ^ ((p & 7) << 4))) =
            (unsigned)f2bf(s0) | ((unsigned)f2bf(s1) << 16);
    }
    __syncthreads();

    // ---- GEMM stream: 54 b128 frag reads + 54 MFMAs per wave, no barriers
    floatx4 acc[3];
#pragma unroll
    for (int n = 0; n < 3; ++n) acc[n] = (floatx4)0.f;
    int rowb[3], mskn[3];
#pragma unroll
    for (int n = 0; n < 3; ++n) {
        int p = (nh + n) * 16 + lr;
        int row = p > 80 ? 80 : p;             // dup rows: results discarded
        rowb[n] = row * 1152;
        mskn[n] = (row & 7) << 4;
    }
#pragma unroll
    for (int s = 0; s < 18; ++s) {
        int cb = s * 64 + lg * 16;
#pragma unroll
        for (int n = 0; n < 3; ++n) {
            bfrag8 bf = *(const bfrag8*)((const char*)vsh + rowb[n] + ((cb ^ mskn[n])));
            acc[n] = __builtin_amdgcn_mfma_f32_16x16x32_bf16(a[s], bf, acc[n], 0, 0, 0);
        }
    }

    // ---- epilogue: bias, pre-BN output, BN2 stats
    float* outb = dout + OUT_H_BASE + (size_t)b * 5184;
#pragma unroll
    for (int j = 0; j < 4; ++j) {
        int o = mt * 16 + lg * 4 + j;
        float bias = bd[o];
        float ss = 0.f, qq = 0.f;
#pragma unroll
        for (int n = 0; n < 3; ++n) {
            int p = (nh + n) * 16 + lr;
            float v = acc[n][j] + bias;
            if (p < 81) { outb[o * 81 + p] = v; ss += v; qq += v * v; }
        }
#pragma unroll
        for (int off = 1; off < 16; off <<= 1) {
            ss += __shfl_xor(ss, off);
            qq += __shfl_xor(qq, off);
        }
        if (lr == 0) { atomicAdd(&sum2[o], ss); atomicAdd(&sq2[o], qq); }
    }
}

// ---------------- launch -------------------------------------------------------
extern "C" void kernel_launch(void* const* d_in, const int* in_sizes, int n_in,
                              void* d_out, int out_size, void* d_ws, size_t ws_size,
                              hipStream_t stream) {
    const float* x   = (const float*)d_in[0];
    const float* w1  = (const float*)d_in[1];
    const float* b1  = (const float*)d_in[2];
    const float* g1  = (const float*)d_in[3];
    const float* be1 = (const float*)d_in[4];
    const float* wo  = (const float*)d_in[5];
    const float* bo  = (const float*)d_in[6];
    const float* wm  = (const float*)d_in[7];
    const float* bm  = (const float*)d_in[8];
    const float* wd  = (const float*)d_in[9];
    const float* bd  = (const float*)d_in[10];
    const float* g2  = (const float*)d_in[11];
    const float* be2 = (const float*)d_in[12];
    float* dout = (float*)d_out;
    float* ws   = (float*)d_ws;

    float* h1    = ws + WS_H1;
    float* maskb = ws + WS_MASK;
    const unsigned short* wdt16 = (const unsigned short*)(ws + WS_WDT);
    const unsigned short* w1m   = (const unsigned short*)(ws + WS_W1M);
    const unsigned short* wcm   = (const unsigned short*)(ws + WS_WCM);
    float* stats = ws + WS_STATS;
    float* sum1 = stats, *sq1 = stats + 64, *sum2 = stats + 128, *sq2 = stats + 192;
    float* scale1 = stats + 256, *shift1 = stats + 320, *scale2 = stats + 384, *shift2 = stats + 448;

    // zero the BN accumulators (ws is NOT re-poisoned between replays)
    hipMemsetAsync(stats, 0, 256 * sizeof(float), stream);

    prep_weights<<<312, 256, 0, stream>>>(w1, wo, wm, wd, ws);
    conv1_mfma<<<BATCH, 256, 0, stream>>>(x, b1, w1m, h1, sum1, sq1);
    bn_finalize<<<1, 64, 0, stream>>>(sum1, sq1, g1, be1, scale1, shift1);
    offmask_mfma<<<BATCH, 256, 0, stream>>>(h1, wcm, bo, bm, scale1, shift1, dout, maskb);
    deform_mfma<<<BATCH, 512, 0, stream>>>(h1, wdt16, maskb, bd, scale1, shift1, dout, sum2, sq2);
    bn_finalize<<<1, 64, 0, stream>>>(sum2, sq2, g2, be2, scale2, shift2);
    bn_apply<<<2048, 256, 0, stream>>>(dout + OUT_H_BASE, scale2, shift2, BATCH * 5184, 1, dout);
}

// Round 5
// 512.225 us; speedup vs baseline: 1.3571x; 1.3571x over previous
//
#include <hip/hip_runtime.h>
#include <hip/hip_bf16.h>

// Problem constants
#define BATCH   2048
#define HW      81          // 9x9
#define CIN     39
#define NPIX    (BATCH*HW)  // 165888

// ws layout (float offsets)
#define WS_H1     0              // 10,616,832 floats  (B,64,81)  PRE-BN h
#define WS_MASK   10616832       // 1,492,992 floats   (B,9,81)
#define WS_WDT    12109824       // 36,864 ushort bf16 [k][o][c]   (18,432 floats)
#define WS_W1M    12128256       // 24,576 ushort bf16 [12][64][32] (12,288 floats)
#define WS_WCM    12140544       // 18,432 ushort bf16 [18][32][32] (9,216 floats)
#define WS_STATS  12149760       // 512 floats: sum1,sq1,sum2,sq2,scale1,shift1,scale2,shift2

#define OUT_OFF_BASE 1
#define OUT_H_BASE   (1 + BATCH*18*81)   // 2985985

typedef __attribute__((ext_vector_type(8))) short bfrag8;
typedef __attribute__((ext_vector_type(4))) float floatx4;

__device__ __forceinline__ unsigned short f2bf(float f) {
    unsigned u = __builtin_bit_cast(unsigned, f);
    u += 0x7FFFu + ((u >> 16) & 1u);       // round-to-nearest-even
    return (unsigned short)(u >> 16);
}
__device__ __forceinline__ float bfhi2f(unsigned hi16) {   // hi16 already in bits 31..16
    return __builtin_bit_cast(float, hi16);
}

// ---------------- weight prep: fragment-ready bf16 layouts --------------------
// w1m: [s(12)][o(64)][kk(32)]  k-map: s<9: (tap=s, c=kk); s=9: (tap=kk>>3, c=32+(kk&7));
//      s=10: (tap=4+(kk>>3), c=32+(kk&7)); s=11: (tap=8, c=32+(kk&7)) for kk<8 else 0.
// wcm: [s(18)][oc(32)][kk(32)] k-map: tap=s>>1, c=(s&1)*32+kk. oc>=27 rows zero.
// wdt: [k(9)][o(64)][c(64)] bf16 (deform)
__global__ void prep_weights(const float* __restrict__ w1, const float* __restrict__ wo,
                             const float* __restrict__ wm, const float* __restrict__ wd,
                             float* __restrict__ ws) {
    int idx = blockIdx.x * 256 + threadIdx.x;
    unsigned short* w1m = (unsigned short*)(ws + WS_W1M);
    unsigned short* wcm = (unsigned short*)(ws + WS_WCM);
    unsigned short* wdt16 = (unsigned short*)(ws + WS_WDT);
    if (idx < 24576) {
        int kk = idx & 31, o = (idx >> 5) & 63, s = idx >> 11;
        int tap, c; bool ok = true;
        if (s < 9)       { tap = s;             c = kk; }
        else if (s == 9) { tap = kk >> 3;       c = 32 + (kk & 7); }
        else if (s == 10){ tap = 4 + (kk >> 3); c = 32 + (kk & 7); }
        else             { tap = 8;             c = 32 + (kk & 7); ok = (kk < 8); }
        float v = (ok && c < CIN) ? w1[(o * CIN + c) * 9 + tap] : 0.f;
        w1m[idx] = f2bf(v);
        return;
    }
    int j = idx - 24576;
    if (j >= 0 && j < 18432) {
        int kk = j & 31, oc = (j >> 5) & 31, s = j >> 10;
        int tap = s >> 1, c = (s & 1) * 32 + kk;
        float v = 0.f;
        if (oc < 18)      v = wo[(oc * 64 + c) * 9 + tap];
        else if (oc < 27) v = wm[((oc - 18) * 64 + c) * 9 + tap];
        wcm[j] = f2bf(v);
        return;
    }
    int m = idx - 24576 - 18432;
    if (m >= 0 && m < 36864) {
        int c = m & 63, o = (m >> 6) & 63, k = m >> 12;
        wdt16[m] = f2bf(wd[(o * 64 + c) * 9 + k]);
    }
}

// ---------------- conv1 (39->64) MFMA + ReLU + BN1 stats ----------------------
__global__ __launch_bounds__(256) void conv1_mfma(
        const float* __restrict__ xg, const float* __restrict__ b1,
        const unsigned short* __restrict__ w1m, float* __restrict__ h1,
        float* __restrict__ sum1, float* __restrict__ sq1) {
    __shared__ short xs[128 * 64];   // [r(121)][c(64)] bf16, byte ^= (r&7)<<4
    int b = blockIdx.x, t = threadIdx.x;
    for (int i = t; i < 4096; i += 256) ((unsigned*)xs)[i] = 0u;
    __syncthreads();
    const float* xb = xg + (size_t)b * (HW * CIN);
    for (int i = t; i < HW * CIN; i += 256) {
        int p = i / 39, c = i - 39 * p;
        int y = p / 9, xx = p - 9 * y;
        int r = (y + 1) * 11 + xx + 1;
        int byte = r * 128 + ((c * 2) ^ ((r & 7) << 4));
        xs[byte >> 1] = (short)f2bf(xb[i]);
    }
    __syncthreads();
    int lane = t & 63, wv = t >> 6, lg = lane >> 4, lr = lane & 15;
    int o = wv * 16 + lr;
    bfrag8 a[12];
#pragma unroll
    for (int s = 0; s < 12; ++s)
        a[s] = *(const bfrag8*)&w1m[(s * 64 + o) * 32 + lg * 8];
    floatx4 acc[6];
#pragma unroll
    for (int n = 0; n < 6; ++n) acc[n] = (floatx4)0.f;
#pragma unroll
    for (int n = 0; n < 6; ++n) {
        int p = n * 16 + lr; p = p > 80 ? 80 : p;
        int y = p / 9, xx = p - 9 * y;
        int rb = (y + 1) * 11 + xx + 1;
#pragma unroll
        for (int s = 0; s < 12; ++s) {
            int r, cb;
            if (s < 9)       { r = rb + (s / 3 - 1) * 11 + (s % 3) - 1; cb = lg * 16; }
            else if (s == 9) { r = rb + (lg / 3 - 1) * 11 + (lg % 3) - 1; cb = 64; }
            else if (s == 10){ int tp = lg + 4; r = rb + (tp / 3 - 1) * 11 + (tp % 3) - 1; cb = 64; }
            else             { r = rb + 12; cb = 64; }
            int byte = r * 128 + (cb ^ ((r & 7) << 4));
            bfrag8 bf = *(const bfrag8*)((const char*)xs + byte);
            acc[n] = __builtin_amdgcn_mfma_f32_16x16x32_bf16(a[s], bf, acc[n], 0, 0, 0);
        }
    }
    float* h1b = h1 + (size_t)b * 5184;
#pragma unroll
    for (int j = 0; j < 4; ++j) {
        int oo = wv * 16 + lg * 4 + j;
        float bias = b1[oo];
        float ss = 0.f, qq = 0.f;
#pragma unroll
        for (int n = 0; n < 6; ++n) {
            int p = n * 16 + lr;
            float v = fmaxf(acc[n][j] + bias, 0.f);
            if (p < 81) { h1b[oo * 81 + p] = v; ss += v; qq += v * v; }
        }
#pragma unroll
        for (int off = 1; off < 16; off <<= 1) { ss += __shfl_xor(ss, off); qq += __shfl_xor(qq, off); }
        if (lr == 0) { atomicAdd(&sum1[oo], ss); atomicAdd(&sq1[oo], qq); }
    }
}

// ---------------- BN finalize -------------------------------------------------
__global__ void bn_finalize(const float* __restrict__ sums, const float* __restrict__ sqs,
                            const float* __restrict__ gamma, const float* __restrict__ beta,
                            float* __restrict__ scale, float* __restrict__ shift) {
    int t = threadIdx.x;   // 64
    float m = sums[t] / (float)NPIX;
    float v = sqs[t] / (float)NPIX - m * m;
    float sc = gamma[t] * (1.f / sqrtf(v + 1e-5f));
    scale[t] = sc;
    shift[t] = beta[t] - m * sc;
}

// ---------------- BN apply (final output) -------------------------------------
__global__ void bn_apply(float* __restrict__ data, const float* __restrict__ scale,
                         const float* __restrict__ shift, int n, int writeProb,
                         float* __restrict__ dout) {
    int i = blockIdx.x * blockDim.x + threadIdx.x;
    if (writeProb && i == 0) dout[0] = 0.5f;
    for (; i < n; i += gridDim.x * blockDim.x) {
        int c = (i / 81) & 63;
        data[i] = data[i] * scale[c] + shift[c];
    }
}

// ---------------- offset(18) + mask(9, sigmoid) conv, MFMA --------------------
__global__ __launch_bounds__(256) void offmask_mfma(
        const float* __restrict__ h1, const unsigned short* __restrict__ wcm,
        const float* __restrict__ bo, const float* __restrict__ bm,
        const float* __restrict__ scale1, const float* __restrict__ shift1,
        float* __restrict__ dout, float* __restrict__ maskbuf) {
    __shared__ float hsh[5184];
    __shared__ short xs[128 * 64];   // padded swizzled bf16 post-BN image
    __shared__ float sc[64], sh[64];
    int b = blockIdx.x, t = threadIdx.x;
    for (int i = t; i < 4096; i += 256) ((unsigned*)xs)[i] = 0u;
    if (t < 128) { if (t < 64) sc[t] = scale1[t]; else sh[t - 64] = shift1[t - 64]; }
    const float* hb = h1 + (size_t)b * 5184;
    for (int i = t; i < 1296; i += 256) ((float4*)hsh)[i] = ((const float4*)hb)[i];
    __syncthreads();
    for (int i = t; i < 5184; i += 256) {
        int p = i >> 6, c = i & 63;
        float v = hsh[c * 81 + p] * sc[c] + sh[c];
        int y = p / 9, xx = p - 9 * y;
        int r = (y + 1) * 11 + xx + 1;
        int byte = r * 128 + ((c * 2) ^ ((r & 7) << 4));
        xs[byte >> 1] = (short)f2bf(v);
    }
    __syncthreads();
    int lane = t & 63, wv = t >> 6, lg = lane >> 4, lr = lane & 15;
    int mt = wv >> 1, nh = (wv & 1) * 3;
    int ocr = mt * 16 + lr;
    bfrag8 a[18];
#pragma unroll
    for (int s = 0; s < 18; ++s)
        a[s] = *(const bfrag8*)&wcm[(s * 32 + ocr) * 32 + lg * 8];
    floatx4 acc[3];
#pragma unroll
    for (int n = 0; n < 3; ++n) acc[n] = (floatx4)0.f;
#pragma unroll
    for (int ni = 0; ni < 3; ++ni) {
        int p = (nh + ni) * 16 + lr; p = p > 80 ? 80 : p;
        int y = p / 9, xx = p - 9 * y;
        int rb = (y + 1) * 11 + xx + 1;
#pragma unroll
        for (int s = 0; s < 18; ++s) {
            int tap = s >> 1, ch = s & 1;
            int r = rb + (tap / 3 - 1) * 11 + (tap % 3) - 1;
            int byte = r * 128 + ((ch * 64 + lg * 16) ^ ((r & 7) << 4));
            bfrag8 bf = *(const bfrag8*)((const char*)xs + byte);
            acc[ni] = __builtin_amdgcn_mfma_f32_16x16x32_bf16(a[s], bf, acc[ni], 0, 0, 0);
        }
    }
#pragma unroll
    for (int j = 0; j < 4; ++j) {
        int oc = mt * 16 + lg * 4 + j;
        if (oc < 18) {
            float bias = bo[oc];
            float* ob = dout + OUT_OFF_BASE + (size_t)b * 1458 + oc * 81;
#pragma unroll
            for (int ni = 0; ni < 3; ++ni) {
                int p = (nh + ni) * 16 + lr;
                if (p < 81) ob[p] = acc[ni][j] + bias;
            }
        } else if (oc < 27) {
            float bias = bm[oc - 18];
            float* mb = maskbuf + (size_t)b * 729 + (oc - 18) * 81;
#pragma unroll
            for (int ni = 0; ni < 3; ++ni) {
                int p = (nh + ni) * 16 + lr;
                if (p < 81) { float v = acc[ni][j] + bias; mb[p] = 1.f / (1.f + expf(-v)); }
            }
        }
    }
}

// ---------------- deformable conv (MFMA, per-tap dbuf, 3 blocks/CU) -----------
// Round-2 pipeline + round-4 verified wins: A-weights in registers (no wk LDS),
// vt rows 128B XOR-swizzled (conflict-free b128 frag reads), LDS ~49KB.
__global__ __launch_bounds__(256) void deform_mfma(
        const float* __restrict__ h1, const unsigned short* __restrict__ wdt16,
        const float* __restrict__ maskbuf, const float* __restrict__ bd,
        const float* __restrict__ scale1, const float* __restrict__ shift1,
        float* __restrict__ dout, float* __restrict__ sum2, float* __restrict__ sq2) {
    __shared__ float    hsh[5184];       // [c][81] f32 post-BN (20736 B)
    __shared__ uint2    bwt[729];        // packed bf16 bilinear weights (5832 B)
    __shared__ unsigned bix[729];        // 4x u8 corner indices (2916 B)
    __shared__ short    vt[2][81 * 64];  // [p][c] bf16, byte ^= (p&7)<<4 (2x10368 B)
    __shared__ float    bdsh[64];

    int b = blockIdx.x, t = threadIdx.x;
    int lane = t & 63, wv = t >> 6, lg = lane >> 4, lr = lane & 15;

    // ---- A fragments from L2-hot global, issued first (72 VGPRs)
    int o = wv * 16 + lr;
    bfrag8 a[18];
#pragma unroll
    for (int s = 0; s < 18; ++s) {
        int k = s >> 1, ks = s & 1;
        a[s] = *(const bfrag8*)&wdt16[(k * 64 + o) * 64 + ks * 32 + lg * 8];
    }
    if (t < 64) bdsh[t] = bd[t];

    // ---- stage h ([c][p], BN1 folded)
    const float* hb = h1 + (size_t)b * 5184;
    for (int i = t; i < 5184; i += 256) {
        int c = i / 81;
        hsh[i] = hb[i] * scale1[c] + shift1[c];
    }

    // ---- bilinear params once per (tap,pixel)
    const float* goff = dout + OUT_OFF_BASE + (size_t)b * 1458;
    const float* gmsk = maskbuf + (size_t)b * 729;
    for (int i = t; i < 729; i += 256) {
        int k = i / 81, p = i - k * 81;
        float dy = goff[(2 * k) * 81 + p];
        float dx = goff[(2 * k + 1) * 81 + p];
        float m  = gmsk[i];
        int y = p / 9, xx = p - y * 9;
        float py = dy + (float)(y + k / 3 - 1);
        float px = dx + (float)(xx + (k % 3) - 1);
        float fy = floorf(py), fx = floorf(px);
        float ly = py - fy, lx = px - fx;
        int y0 = (int)fy, x0 = (int)fx;
        int y1 = y0 + 1, x1 = x0 + 1;
        bool vy0 = (y0 >= 0) & (y0 < 9), vy1 = (y1 >= 0) & (y1 < 9);
        bool vx0 = (x0 >= 0) & (x0 < 9), vx1 = (x1 >= 0) & (x1 < 9);
        float w00 = (vy0 && vx0) ? m * (1.f - ly) * (1.f - lx) : 0.f;
        float w01 = (vy0 && vx1) ? m * (1.f - ly) * lx : 0.f;
        float w10 = (vy1 && vx0) ? m * ly * (1.f - lx) : 0.f;
        float w11 = (vy1 && vx1) ? m * ly * lx : 0.f;
        int yc0 = min(max(y0, 0), 8), yc1 = min(max(y1, 0), 8);
        int xc0 = min(max(x0, 0), 8), xc1 = min(max(x1, 0), 8);
        unsigned i00 = yc0 * 9 + xc0, i01 = yc0 * 9 + xc1;
        unsigned i10 = yc1 * 9 + xc0, i11 = yc1 * 9 + xc1;
        bwt[i] = make_uint2((unsigned)f2bf(w00) | ((unsigned)f2bf(w01) << 16),
                            (unsigned)f2bf(w10) | ((unsigned)f2bf(w11) << 16));
        bix[i] = i00 | (i01 << 8) | (i10 << 16) | (i11 << 24);
    }
    __syncthreads();

    // ---- fill tap kk into vt[nb]: 81p x 32 channel-pairs
    auto stage_tap = [&](int kk, int nb) {
        int kbase = kk * 81;
        for (int i = t; i < 2592; i += 256) {
            int c2 = i & 31, p = i >> 5;           // 32 lanes share p
            uint2 bw = bwt[kbase + p];
            unsigned ix = bix[kbase + p];
            float w00 = bfhi2f(bw.x << 16), w01 = bfhi2f(bw.x & 0xffff0000u);
            float w10 = bfhi2f(bw.y << 16), w11 = bfhi2f(bw.y & 0xffff0000u);
            int i00 = ix & 255, i01 = (ix >> 8) & 255, i10 = (ix >> 16) & 255, i11 = ix >> 24;
            const float* h0 = &hsh[(2 * c2) * 81];
            const float* h1r = h0 + 81;
            float s0 = w00 * h0[i00] + w01 * h0[i01] + w10 * h0[i10] + w11 * h0[i11];
            float s1 = w00 * h1r[i00] + w01 * h1r[i01] + w10 * h1r[i10] + w11 * h1r[i11];
            *(unsigned*)((char*)vt[nb] + p * 128 + ((c2 * 4) ^ ((p & 7) << 4))) =
                (unsigned)f2bf(s0) | ((unsigned)f2bf(s1) << 16);
        }
    };

    stage_tap(0, 0);
    __syncthreads();

    floatx4 acc[6];
#pragma unroll
    for (int n = 0; n < 6; ++n) acc[n] = (floatx4)0.f;
    int rowb[6], swzn[6];
#pragma unroll
    for (int n = 0; n < 6; ++n) {
        int row = n * 16 + lr; row = row > 80 ? 80 : row;
        rowb[n] = row * 128;
        swzn[n] = (row & 7) << 4;
    }

#pragma unroll
    for (int k = 0; k < 9; ++k) {
        int cur = k & 1;
        if (k < 8) stage_tap(k + 1, cur ^ 1);
        const char* vb = (const char*)vt[cur];
#pragma unroll
        for (int n = 0; n < 6; ++n) {
            bfrag8 b0 = *(const bfrag8*)(vb + rowb[n] + ((lg * 16) ^ swzn[n]));
            bfrag8 b1 = *(const bfrag8*)(vb + rowb[n] + ((64 + lg * 16) ^ swzn[n]));
            acc[n] = __builtin_amdgcn_mfma_f32_16x16x32_bf16(a[2 * k], b0, acc[n], 0, 0, 0);
            acc[n] = __builtin_amdgcn_mfma_f32_16x16x32_bf16(a[2 * k + 1], b1, acc[n], 0, 0, 0);
        }
        __syncthreads();   // one barrier/tap: covers dbuf reuse + next-tap fill
    }

    // ---- epilogue: bias, pre-BN output, BN2 stats
    float* outb = dout + OUT_H_BASE + (size_t)b * 5184;
#pragma unroll
    for (int j = 0; j < 4; ++j) {
        int oo = wv * 16 + lg * 4 + j;
        float bias = bdsh[oo];
        float ss = 0.f, qq = 0.f;
#pragma unroll
        for (int n = 0; n < 6; ++n) {
            int p = n * 16 + lr;
            float v = acc[n][j] + bias;
            if (p < 81) { outb[oo * 81 + p] = v; ss += v; qq += v * v; }
        }
#pragma unroll
        for (int off = 1; off < 16; off <<= 1) {
            ss += __shfl_xor(ss, off);
            qq += __shfl_xor(qq, off);
        }
        if (lr == 0) { atomicAdd(&sum2[oo], ss); atomicAdd(&sq2[oo], qq); }
    }
}

// ---------------- launch -------------------------------------------------------
extern "C" void kernel_launch(void* const* d_in, const int* in_sizes, int n_in,
                              void* d_out, int out_size, void* d_ws, size_t ws_size,
                              hipStream_t stream) {
    const float* x   = (const float*)d_in[0];
    const float* w1  = (const float*)d_in[1];
    const float* b1  = (const float*)d_in[2];
    const float* g1  = (const float*)d_in[3];
    const float* be1 = (const float*)d_in[4];
    const float* wo  = (const float*)d_in[5];
    const float* bo  = (const float*)d_in[6];
    const float* wm  = (const float*)d_in[7];
    const float* bm  = (const float*)d_in[8];
    const float* wd  = (const float*)d_in[9];
    const float* bd  = (const float*)d_in[10];
    const float* g2  = (const float*)d_in[11];
    const float* be2 = (const float*)d_in[12];
    float* dout = (float*)d_out;
    float* ws   = (float*)d_ws;

    float* h1    = ws + WS_H1;
    float* maskb = ws + WS_MASK;
    const unsigned short* wdt16 = (const unsigned short*)(ws + WS_WDT);
    const unsigned short* w1m   = (const unsigned short*)(ws + WS_W1M);
    const unsigned short* wcm   = (const unsigned short*)(ws + WS_WCM);
    float* stats = ws + WS_STATS;
    float* sum1 = stats, *sq1 = stats + 64, *sum2 = stats + 128, *sq2 = stats + 192;
    float* scale1 = stats + 256, *shift1 = stats + 320, *scale2 = stats + 384, *shift2 = stats + 448;

    // zero the BN accumulators (ws is NOT re-poisoned between replays)
    hipMemsetAsync(stats, 0, 256 * sizeof(float), stream);

    prep_weights<<<312, 256, 0, stream>>>(w1, wo, wm, wd, ws);
    conv1_mfma<<<BATCH, 256, 0, stream>>>(x, b1, w1m, h1, sum1, sq1);
    bn_finalize<<<1, 64, 0, stream>>>(sum1, sq1, g1, be1, scale1, shift1);
    offmask_mfma<<<BATCH, 256, 0, stream>>>(h1, wcm, bo, bm, scale1, shift1, dout, maskb);
    deform_mfma<<<BATCH, 256, 0, stream>>>(h1, wdt16, maskb, bd, scale1, shift1, dout, sum2, sq2);
    bn_finalize<<<1, 64, 0, stream>>>(sum2, sq2, g2, be2, scale2, shift2);
    bn_apply<<<2048, 256, 0, stream>>>(dout + OUT_H_BASE, scale2, shift2, BATCH * 5184, 1, dout);
}

// Round 6
// 493.294 us; speedup vs baseline: 1.4091x; 1.0384x over previous
//
#include <hip/hip_runtime.h>
#include <hip/hip_bf16.h>

// Problem constants
#define BATCH   2048
#define HW      81          // 9x9
#define CIN     39
#define NPIX    (BATCH*HW)  // 165888

// ws layout (float offsets)
#define WS_H1     0              // 10,616,832 floats  (B,64,81)  PRE-BN h
#define WS_MASK   10616832       // 1,492,992 floats   (B,9,81)
#define WS_WDT    12109824       // 36,864 ushort bf16 [k][o][c]   (18,432 floats)
#define WS_W1M    12128256       // 24,576 ushort bf16 [12][64][32] (12,288 floats)
#define WS_WCM    12140544       // 18,432 ushort bf16 [18][32][32] (9,216 floats)
#define WS_STATS  12149760       // 512 floats: sum1,sq1,sum2,sq2,scale1,shift1,scale2,shift2

#define OUT_OFF_BASE 1
#define OUT_H_BASE   (1 + BATCH*18*81)   // 2985985

typedef __attribute__((ext_vector_type(8))) short bfrag8;
typedef __attribute__((ext_vector_type(4))) float floatx4;

__device__ __forceinline__ unsigned short f2bf(float f) {
    unsigned u = __builtin_bit_cast(unsigned, f);
    u += 0x7FFFu + ((u >> 16) & 1u);       // round-to-nearest-even
    return (unsigned short)(u >> 16);
}
__device__ __forceinline__ float bfhi2f(unsigned hi16) {   // hi16 already in bits 31..16
    return __builtin_bit_cast(float, hi16);
}

// ---------------- weight prep: fragment-ready bf16 layouts --------------------
// w1m: [s(12)][o(64)][kk(32)]  k-map: s<9: (tap=s, c=kk); s=9: (tap=kk>>3, c=32+(kk&7));
//      s=10: (tap=4+(kk>>3), c=32+(kk&7)); s=11: (tap=8, c=32+(kk&7)) for kk<8 else 0.
// wcm: [s(18)][oc(32)][kk(32)] k-map: tap=s>>1, c=(s&1)*32+kk. oc>=27 rows zero.
// wdt: [k(9)][o(64)][c(64)] bf16 (deform)
__global__ void prep_weights(const float* __restrict__ w1, const float* __restrict__ wo,
                             const float* __restrict__ wm, const float* __restrict__ wd,
                             float* __restrict__ ws) {
    int idx = blockIdx.x * 256 + threadIdx.x;
    unsigned short* w1m = (unsigned short*)(ws + WS_W1M);
    unsigned short* wcm = (unsigned short*)(ws + WS_WCM);
    unsigned short* wdt16 = (unsigned short*)(ws + WS_WDT);
    if (idx < 24576) {
        int kk = idx & 31, o = (idx >> 5) & 63, s = idx >> 11;
        int tap, c; bool ok = true;
        if (s < 9)       { tap = s;             c = kk; }
        else if (s == 9) { tap = kk >> 3;       c = 32 + (kk & 7); }
        else if (s == 10){ tap = 4 + (kk >> 3); c = 32 + (kk & 7); }
        else             { tap = 8;             c = 32 + (kk & 7); ok = (kk < 8); }
        float v = (ok && c < CIN) ? w1[(o * CIN + c) * 9 + tap] : 0.f;
        w1m[idx] = f2bf(v);
        return;
    }
    int j = idx - 24576;
    if (j >= 0 && j < 18432) {
        int kk = j & 31, oc = (j >> 5) & 31, s = j >> 10;
        int tap = s >> 1, c = (s & 1) * 32 + kk;
        float v = 0.f;
        if (oc < 18)      v = wo[(oc * 64 + c) * 9 + tap];
        else if (oc < 27) v = wm[((oc - 18) * 64 + c) * 9 + tap];
        wcm[j] = f2bf(v);
        return;
    }
    int m = idx - 24576 - 18432;
    if (m >= 0 && m < 36864) {
        int c = m & 63, o = (m >> 6) & 63, k = m >> 12;
        wdt16[m] = f2bf(wd[(o * 64 + c) * 9 + k]);
    }
}

// ---------------- conv1 (39->64) MFMA + ReLU + BN1 stats ----------------------
__global__ __launch_bounds__(256) void conv1_mfma(
        const float* __restrict__ xg, const float* __restrict__ b1,
        const unsigned short* __restrict__ w1m, float* __restrict__ h1,
        float* __restrict__ sum1, float* __restrict__ sq1) {
    __shared__ short xs[128 * 64];   // [r(121)][c(64)] bf16, byte ^= (r&7)<<4
    int b = blockIdx.x, t = threadIdx.x;
    for (int i = t; i < 4096; i += 256) ((unsigned*)xs)[i] = 0u;
    __syncthreads();
    const float* xb = xg + (size_t)b * (HW * CIN);
    for (int i = t; i < HW * CIN; i += 256) {
        int p = i / 39, c = i - 39 * p;
        int y = p / 9, xx = p - 9 * y;
        int r = (y + 1) * 11 + xx + 1;
        int byte = r * 128 + ((c * 2) ^ ((r & 7) << 4));
        xs[byte >> 1] = (short)f2bf(xb[i]);
    }
    __syncthreads();
    int lane = t & 63, wv = t >> 6, lg = lane >> 4, lr = lane & 15;
    int o = wv * 16 + lr;
    bfrag8 a[12];
#pragma unroll
    for (int s = 0; s < 12; ++s)
        a[s] = *(const bfrag8*)&w1m[(s * 64 + o) * 32 + lg * 8];
    floatx4 acc[6];
#pragma unroll
    for (int n = 0; n < 6; ++n) acc[n] = (floatx4)0.f;
#pragma unroll
    for (int n = 0; n < 6; ++n) {
        int p = n * 16 + lr; p = p > 80 ? 80 : p;
        int y = p / 9, xx = p - 9 * y;
        int rb = (y + 1) * 11 + xx + 1;
#pragma unroll
        for (int s = 0; s < 12; ++s) {
            int r, cb;
            if (s < 9)       { r = rb + (s / 3 - 1) * 11 + (s % 3) - 1; cb = lg * 16; }
            else if (s == 9) { r = rb + (lg / 3 - 1) * 11 + (lg % 3) - 1; cb = 64; }
            else if (s == 10){ int tp = lg + 4; r = rb + (tp / 3 - 1) * 11 + (tp % 3) - 1; cb = 64; }
            else             { r = rb + 12; cb = 64; }
            int byte = r * 128 + (cb ^ ((r & 7) << 4));
            bfrag8 bf = *(const bfrag8*)((const char*)xs + byte);
            acc[n] = __builtin_amdgcn_mfma_f32_16x16x32_bf16(a[s], bf, acc[n], 0, 0, 0);
        }
    }
    float* h1b = h1 + (size_t)b * 5184;
#pragma unroll
    for (int j = 0; j < 4; ++j) {
        int oo = wv * 16 + lg * 4 + j;
        float bias = b1[oo];
        float ss = 0.f, qq = 0.f;
#pragma unroll
        for (int n = 0; n < 6; ++n) {
            int p = n * 16 + lr;
            float v = fmaxf(acc[n][j] + bias, 0.f);
            if (p < 81) { h1b[oo * 81 + p] = v; ss += v; qq += v * v; }
        }
#pragma unroll
        for (int off = 1; off < 16; off <<= 1) { ss += __shfl_xor(ss, off); qq += __shfl_xor(qq, off); }
        if (lr == 0) { atomicAdd(&sum1[oo], ss); atomicAdd(&sq1[oo], qq); }
    }
}

// ---------------- BN finalize -------------------------------------------------
__global__ void bn_finalize(const float* __restrict__ sums, const float* __restrict__ sqs,
                            const float* __restrict__ gamma, const float* __restrict__ beta,
                            float* __restrict__ scale, float* __restrict__ shift) {
    int t = threadIdx.x;   // 64
    float m = sums[t] / (float)NPIX;
    float v = sqs[t] / (float)NPIX - m * m;
    float sc = gamma[t] * (1.f / sqrtf(v + 1e-5f));
    scale[t] = sc;
    shift[t] = beta[t] - m * sc;
}

// ---------------- BN apply (final output) -------------------------------------
__global__ void bn_apply(float* __restrict__ data, const float* __restrict__ scale,
                         const float* __restrict__ shift, int n, int writeProb,
                         float* __restrict__ dout) {
    int i = blockIdx.x * blockDim.x + threadIdx.x;
    if (writeProb && i == 0) dout[0] = 0.5f;
    for (; i < n; i += gridDim.x * blockDim.x) {
        int c = (i / 81) & 63;
        data[i] = data[i] * scale[c] + shift[c];
    }
}

// ---------------- offset(18) + mask(9, sigmoid) conv, MFMA --------------------
__global__ __launch_bounds__(256) void offmask_mfma(
        const float* __restrict__ h1, const unsigned short* __restrict__ wcm,
        const float* __restrict__ bo, const float* __restrict__ bm,
        const float* __restrict__ scale1, const float* __restrict__ shift1,
        float* __restrict__ dout, float* __restrict__ maskbuf) {
    __shared__ float hsh[5184];
    __shared__ short xs[128 * 64];   // padded swizzled bf16 post-BN image
    __shared__ float sc[64], sh[64];
    int b = blockIdx.x, t = threadIdx.x;
    for (int i = t; i < 4096; i += 256) ((unsigned*)xs)[i] = 0u;
    if (t < 128) { if (t < 64) sc[t] = scale1[t]; else sh[t - 64] = shift1[t - 64]; }
    const float* hb = h1 + (size_t)b * 5184;
    for (int i = t; i < 1296; i += 256) ((float4*)hsh)[i] = ((const float4*)hb)[i];
    __syncthreads();
    for (int i = t; i < 5184; i += 256) {
        int p = i >> 6, c = i & 63;
        float v = hsh[c * 81 + p] * sc[c] + sh[c];
        int y = p / 9, xx = p - 9 * y;
        int r = (y + 1) * 11 + xx + 1;
        int byte = r * 128 + ((c * 2) ^ ((r & 7) << 4));
        xs[byte >> 1] = (short)f2bf(v);
    }
    __syncthreads();
    int lane = t & 63, wv = t >> 6, lg = lane >> 4, lr = lane & 15;
    int mt = wv >> 1, nh = (wv & 1) * 3;
    int ocr = mt * 16 + lr;
    bfrag8 a[18];
#pragma unroll
    for (int s = 0; s < 18; ++s)
        a[s] = *(const bfrag8*)&wcm[(s * 32 + ocr) * 32 + lg * 8];
    floatx4 acc[3];
#pragma unroll
    for (int n = 0; n < 3; ++n) acc[n] = (floatx4)0.f;
#pragma unroll
    for (int ni = 0; ni < 3; ++ni) {
        int p = (nh + ni) * 16 + lr; p = p > 80 ? 80 : p;
        int y = p / 9, xx = p - 9 * y;
        int rb = (y + 1) * 11 + xx + 1;
#pragma unroll
        for (int s = 0; s < 18; ++s) {
            int tap = s >> 1, ch = s & 1;
            int r = rb + (tap / 3 - 1) * 11 + (tap % 3) - 1;
            int byte = r * 128 + ((ch * 64 + lg * 16) ^ ((r & 7) << 4));
            bfrag8 bf = *(const bfrag8*)((const char*)xs + byte);
            acc[ni] = __builtin_amdgcn_mfma_f32_16x16x32_bf16(a[s], bf, acc[ni], 0, 0, 0);
        }
    }
#pragma unroll
    for (int j = 0; j < 4; ++j) {
        int oc = mt * 16 + lg * 4 + j;
        if (oc < 18) {
            float bias = bo[oc];
            float* ob = dout + OUT_OFF_BASE + (size_t)b * 1458 + oc * 81;
#pragma unroll
            for (int ni = 0; ni < 3; ++ni) {
                int p = (nh + ni) * 16 + lr;
                if (p < 81) ob[p] = acc[ni][j] + bias;
            }
        } else if (oc < 27) {
            float bias = bm[oc - 18];
            float* mb = maskbuf + (size_t)b * 729 + (oc - 18) * 81;
#pragma unroll
            for (int ni = 0; ni < 3; ++ni) {
                int p = (nh + ni) * 16 + lr;
                if (p < 81) { float v = acc[ni][j] + bias; mb[p] = 1.f / (1.f + expf(-v)); }
            }
        }
    }
}

// ---------------- deformable conv (MFMA, per-tap dbuf, static-unrolled fill) ---
// hsh [q][256B] f32 rows, 8B-XOR swizzle -> float2 corner reads conflict-free.
// bix holds pre-swizzled u16 byte offsets (q*256 + ((q&31)<<3)); use: off ^ c2*8.
// Fill padded to 88 p-rows = exactly 11 items/thread, fully unrolled for ILP.
// vt [p][128B] rows, 16B-XOR swizzle; A-weights in regs; 3 blocks/CU (54.2KB).
__global__ __launch_bounds__(256) void deform_mfma(
        const float* __restrict__ h1, const unsigned short* __restrict__ wdt16,
        const float* __restrict__ maskbuf, const float* __restrict__ bd,
        const float* __restrict__ scale1, const float* __restrict__ shift1,
        float* __restrict__ dout, float* __restrict__ sum2, float* __restrict__ sq2) {
    __shared__ float    hsh[81 * 64];    // byte: q*256 + ((c*4) ^ ((q&31)<<3))  (20736 B)
    __shared__ uint2    bwt[729];        // packed bf16 bilinear weights (5832 B)
    __shared__ uint2    bix[729];        // 4x u16 pre-swizzled byte offsets (5832 B)
    __shared__ short    vt[2][82 * 64];  // byte: p*128 + ((c*2) ^ ((p&7)<<4)) (20992 B)
    __shared__ float    bdsh[64], scs[64], shs[64];

    int b = blockIdx.x, t = threadIdx.x;
    int lane = t & 63, wv = t >> 6, lg = lane >> 4, lr = lane & 15;

    // ---- A fragments from L2-hot global, issued first (72 VGPRs)
    int o = wv * 16 + lr;
    bfrag8 a[18];
#pragma unroll
    for (int s = 0; s < 18; ++s) {
        int k = s >> 1, ks = s & 1;
        a[s] = *(const bfrag8*)&wdt16[(k * 64 + o) * 64 + ks * 32 + lg * 8];
    }
    if (t < 64) { bdsh[t] = bd[t]; scs[t] = scale1[t]; shs[t] = shift1[t]; }
    __syncthreads();

    // ---- stage h: [q][c] f32, swizzled; BN1 folded
    const float* hb = h1 + (size_t)b * 5184;
    for (int i = t; i < 5184; i += 256) {
        int c = i / 81, q = i - c * 81;
        float v = hb[i] * scs[c] + shs[c];
        *(float*)((char*)hsh + q * 256 + ((c * 4) ^ ((q & 31) << 3))) = v;
    }

    // ---- bilinear params once per (tap,pixel); offsets pre-swizzled
    const float* goff = dout + OUT_OFF_BASE + (size_t)b * 1458;
    const float* gmsk = maskbuf + (size_t)b * 729;
    for (int i = t; i < 729; i += 256) {
        int k = i / 81, p = i - k * 81;
        float dy = goff[(2 * k) * 81 + p];
        float dx = goff[(2 * k + 1) * 81 + p];
        float m  = gmsk[i];
        int y = p / 9, xx = p - y * 9;
        float py = dy + (float)(y + k / 3 - 1);
        float px = dx + (float)(xx + (k % 3) - 1);
        float fy = floorf(py), fx = floorf(px);
        float ly = py - fy, lx = px - fx;
        int y0 = (int)fy, x0 = (int)fx;
        int y1 = y0 + 1, x1 = x0 + 1;
        bool vy0 = (y0 >= 0) & (y0 < 9), vy1 = (y1 >= 0) & (y1 < 9);
        bool vx0 = (x0 >= 0) & (x0 < 9), vx1 = (x1 >= 0) & (x1 < 9);
        float w00 = (vy0 && vx0) ? m * (1.f - ly) * (1.f - lx) : 0.f;
        float w01 = (vy0 && vx1) ? m * (1.f - ly) * lx : 0.f;
        float w10 = (vy1 && vx0) ? m * ly * (1.f - lx) : 0.f;
        float w11 = (vy1 && vx1) ? m * ly * lx : 0.f;
        int yc0 = min(max(y0, 0), 8), yc1 = min(max(y1, 0), 8);
        int xc0 = min(max(x0, 0), 8), xc1 = min(max(x1, 0), 8);
        int q00 = yc0 * 9 + xc0, q01 = yc0 * 9 + xc1;
        int q10 = yc1 * 9 + xc0, q11 = yc1 * 9 + xc1;
        bwt[i] = make_uint2((unsigned)f2bf(w00) | ((unsigned)f2bf(w01) << 16),
                            (unsigned)f2bf(w10) | ((unsigned)f2bf(w11) << 16));
        auto S = [](int q) { return (unsigned)(q * 256 + ((q & 31) << 3)); };
        bix[i] = make_uint2(S(q00) | (S(q01) << 16), S(q10) | (S(q11) << 16));
    }
    __syncthreads();

    // ---- fill tap kk into vt[nb]: 88p x 32 c-pairs = 11 static items/thread
    auto stage_tap = [&](int kk, int nb) {
        int kbase = kk * 81;
        char* vb = (char*)vt[nb];
        const char* hc = (const char*)hsh;
#pragma unroll
        for (int j = 0; j < 11; ++j) {
            int i = t + j * 256;
            int c2 = i & 31, p = i >> 5;           // p in 0..87
            int pr = p > 80 ? 80 : p;
            uint2 bw = bwt[kbase + pr];
            uint2 ix = bix[kbase + pr];
            float w00 = bfhi2f(bw.x << 16), w01 = bfhi2f(bw.x & 0xffff0000u);
            float w10 = bfhi2f(bw.y << 16), w11 = bfhi2f(bw.y & 0xffff0000u);
            int c8 = c2 * 8;
            float2 v00 = *(const float2*)(hc + ((ix.x & 0xffffu) ^ c8));
            float2 v01 = *(const float2*)(hc + ((ix.x >> 16) ^ c8));
            float2 v10 = *(const float2*)(hc + ((ix.y & 0xffffu) ^ c8));
            float2 v11 = *(const float2*)(hc + ((ix.y >> 16) ^ c8));
            float s0 = w00 * v00.x + w01 * v01.x + w10 * v10.x + w11 * v11.x;
            float s1 = w00 * v00.y + w01 * v01.y + w10 * v10.y + w11 * v11.y;
            unsigned pk;
            asm("v_cvt_pk_bf16_f32 %0, %1, %2" : "=v"(pk) : "v"(s0), "v"(s1));
            int pw = p > 81 ? 81 : p;              // row 81 = dummy sink
            *(unsigned*)(vb + pw * 128 + ((c2 * 4) ^ ((pw & 7) << 4))) = pk;
        }
    };

    stage_tap(0, 0);
    __syncthreads();

    floatx4 acc[6];
#pragma unroll
    for (int n = 0; n < 6; ++n) acc[n] = (floatx4)0.f;
    int rowb[6], swzn[6];
#pragma unroll
    for (int n = 0; n < 6; ++n) {
        int row = n * 16 + lr; row = row > 80 ? 80 : row;
        rowb[n] = row * 128;
        swzn[n] = (row & 7) << 4;
    }

#pragma unroll
    for (int k = 0; k < 9; ++k) {
        int cur = k & 1;
        const char* vb = (const char*)vt[cur];
#pragma unroll
        for (int n = 0; n < 6; ++n) {
            bfrag8 b0 = *(const bfrag8*)(vb + rowb[n] + ((lg * 16) ^ swzn[n]));
            bfrag8 b1 = *(const bfrag8*)(vb + rowb[n] + ((64 + lg * 16) ^ swzn[n]));
            acc[n] = __builtin_amdgcn_mfma_f32_16x16x32_bf16(a[2 * k], b0, acc[n], 0, 0, 0);
            acc[n] = __builtin_amdgcn_mfma_f32_16x16x32_bf16(a[2 * k + 1], b1, acc[n], 0, 0, 0);
        }
        if (k < 8) stage_tap(k + 1, cur ^ 1);
        __syncthreads();   // one barrier/tap: covers dbuf reuse + next-tap fill
    }

    // ---- epilogue: bias, pre-BN output, BN2 stats
    float* outb = dout + OUT_H_BASE + (size_t)b * 5184;
#pragma unroll
    for (int j = 0; j < 4; ++j) {
        int oo = wv * 16 + lg * 4 + j;
        float bias = bdsh[oo];
        float ss = 0.f, qq = 0.f;
#pragma unroll
        for (int n = 0; n < 6; ++n) {
            int p = n * 16 + lr;
            float v = acc[n][j] + bias;
            if (p < 81) { outb[oo * 81 + p] = v; ss += v; qq += v * v; }
        }
#pragma unroll
        for (int off = 1; off < 16; off <<= 1) {
            ss += __shfl_xor(ss, off);
            qq += __shfl_xor(qq, off);
        }
        if (lr == 0) { atomicAdd(&sum2[oo], ss); atomicAdd(&sq2[oo], qq); }
    }
}

// ---------------- launch -------------------------------------------------------
extern "C" void kernel_launch(void* const* d_in, const int* in_sizes, int n_in,
                              void* d_out, int out_size, void* d_ws, size_t ws_size,
                              hipStream_t stream) {
    const float* x   = (const float*)d_in[0];
    const float* w1  = (const float*)d_in[1];
    const float* b1  = (const float*)d_in[2];
    const float* g1  = (const float*)d_in[3];
    const float* be1 = (const float*)d_in[4];
    const float* wo  = (const float*)d_in[5];
    const float* bo  = (const float*)d_in[6];
    const float* wm  = (const float*)d_in[7];
    const float* bm  = (const float*)d_in[8];
    const float* wd  = (const float*)d_in[9];
    const float* bd  = (const float*)d_in[10];
    const float* g2  = (const float*)d_in[11];
    const float* be2 = (const float*)d_in[12];
    float* dout = (float*)d_out;
    float* ws   = (float*)d_ws;

    float* h1    = ws + WS_H1;
    float* maskb = ws + WS_MASK;
    const unsigned short* wdt16 = (const unsigned short*)(ws + WS_WDT);
    const unsigned short* w1m   = (const unsigned short*)(ws + WS_W1M);
    const unsigned short* wcm   = (const unsigned short*)(ws + WS_WCM);
    float* stats = ws + WS_STATS;
    float* sum1 = stats, *sq1 = stats + 64, *sum2 = stats + 128, *sq2 = stats + 192;
    float* scale1 = stats + 256, *shift1 = stats + 320, *scale2 = stats + 384, *shift2 = stats + 448;

    // zero the BN accumulators (ws is NOT re-poisoned between replays)
    hipMemsetAsync(stats, 0, 256 * sizeof(float), stream);

    prep_weights<<<312, 256, 0, stream>>>(w1, wo, wm, wd, ws);
    conv1_mfma<<<BATCH, 256, 0, stream>>>(x, b1, w1m, h1, sum1, sq1);
    bn_finalize<<<1, 64, 0, stream>>>(sum1, sq1, g1, be1, scale1, shift1);
    offmask_mfma<<<BATCH, 256, 0, stream>>>(h1, wcm, bo, bm, scale1, shift1, dout, maskb);
    deform_mfma<<<BATCH, 256, 0, stream>>>(h1, wdt16, maskb, bd, scale1, shift1, dout, sum2, sq2);
    bn_finalize<<<1, 64, 0, stream>>>(sum2, sq2, g2, be2, scale2, shift2);
    bn_apply<<<2048, 256, 0, stream>>>(dout + OUT_H_BASE, scale2, shift2, BATCH * 5184, 1, dout);
}

// Round 7
// 162.887 us; speedup vs baseline: 4.2675x; 3.0284x over previous
//
#include <hip/hip_runtime.h>
#include <hip/hip_bf16.h>

// Problem constants
#define BATCH   2048
#define HW      81          // 9x9
#define CIN     39
#define NPIX    (BATCH*HW)  // 165888

// ws layout (float offsets)
#define WS_H1     0              // 10,616,832 floats  (B,64,81)  PRE-BN h
#define WS_MASK   10616832       // 1,492,992 floats   (B,9,81)
#define WS_WDT    12109824       // 36,864 ushort bf16 [k][o][c]   (18,432 floats)
#define WS_W1M    12128256       // 24,576 ushort bf16 [12][64][32] (12,288 floats)
#define WS_WCM    12140544       // 18,432 ushort bf16 [18][32][32] (9,216 floats)
#define WS_STATS  12149760       // 8448 floats: sum1[2048],sq1[2048],sum2[2048],sq2[2048],
                                 //              scale1,shift1,scale2,shift2 (64 each)

#define OUT_OFF_BASE 1
#define OUT_H_BASE   (1 + BATCH*18*81)   // 2985985

typedef __attribute__((ext_vector_type(8))) short bfrag8;
typedef __attribute__((ext_vector_type(4))) float floatx4;

__device__ __forceinline__ unsigned short f2bf(float f) {
    unsigned u = __builtin_bit_cast(unsigned, f);
    u += 0x7FFFu + ((u >> 16) & 1u);       // round-to-nearest-even
    return (unsigned short)(u >> 16);
}
__device__ __forceinline__ float bfhi2f(unsigned hi16) {   // hi16 already in bits 31..16
    return __builtin_bit_cast(float, hi16);
}

// ---------------- weight prep: fragment-ready bf16 layouts --------------------
__global__ void prep_weights(const float* __restrict__ w1, const float* __restrict__ wo,
                             const float* __restrict__ wm, const float* __restrict__ wd,
                             float* __restrict__ ws) {
    int idx = blockIdx.x * 256 + threadIdx.x;
    unsigned short* w1m = (unsigned short*)(ws + WS_W1M);
    unsigned short* wcm = (unsigned short*)(ws + WS_WCM);
    unsigned short* wdt16 = (unsigned short*)(ws + WS_WDT);
    if (idx < 24576) {
        int kk = idx & 31, o = (idx >> 5) & 63, s = idx >> 11;
        int tap, c; bool ok = true;
        if (s < 9)       { tap = s;             c = kk; }
        else if (s == 9) { tap = kk >> 3;       c = 32 + (kk & 7); }
        else if (s == 10){ tap = 4 + (kk >> 3); c = 32 + (kk & 7); }
        else             { tap = 8;             c = 32 + (kk & 7); ok = (kk < 8); }
        float v = (ok && c < CIN) ? w1[(o * CIN + c) * 9 + tap] : 0.f;
        w1m[idx] = f2bf(v);
        return;
    }
    int j = idx - 24576;
    if (j >= 0 && j < 18432) {
        int kk = j & 31, oc = (j >> 5) & 31, s = j >> 10;
        int tap = s >> 1, c = (s & 1) * 32 + kk;
        float v = 0.f;
        if (oc < 18)      v = wo[(oc * 64 + c) * 9 + tap];
        else if (oc < 27) v = wm[((oc - 18) * 64 + c) * 9 + tap];
        wcm[j] = f2bf(v);
        return;
    }
    int m = idx - 24576 - 18432;
    if (m >= 0 && m < 36864) {
        int c = m & 63, o = (m >> 6) & 63, k = m >> 12;
        wdt16[m] = f2bf(wd[(o * 64 + c) * 9 + k]);
    }
}

// ---------------- conv1 (39->64) MFMA + ReLU + BN1 stats ----------------------
__global__ __launch_bounds__(256) void conv1_mfma(
        const float* __restrict__ xg, const float* __restrict__ b1,
        const unsigned short* __restrict__ w1m, float* __restrict__ h1,
        float* __restrict__ sum1, float* __restrict__ sq1) {
    __shared__ short xs[128 * 64];   // [r(121)][c(64)] bf16, byte ^= (r&7)<<4
    int b = blockIdx.x, t = threadIdx.x;
    for (int i = t; i < 4096; i += 256) ((unsigned*)xs)[i] = 0u;
    __syncthreads();
    const float* xb = xg + (size_t)b * (HW * CIN);
    for (int i = t; i < HW * CIN; i += 256) {
        int p = i / 39, c = i - 39 * p;
        int y = p / 9, xx = p - 9 * y;
        int r = (y + 1) * 11 + xx + 1;
        int byte = r * 128 + ((c * 2) ^ ((r & 7) << 4));
        xs[byte >> 1] = (short)f2bf(xb[i]);
    }
    __syncthreads();
    int lane = t & 63, wv = t >> 6, lg = lane >> 4, lr = lane & 15;
    int o = wv * 16 + lr;
    bfrag8 a[12];
#pragma unroll
    for (int s = 0; s < 12; ++s)
        a[s] = *(const bfrag8*)&w1m[(s * 64 + o) * 32 + lg * 8];
    floatx4 acc[6];
#pragma unroll
    for (int n = 0; n < 6; ++n) acc[n] = (floatx4)0.f;
#pragma unroll
    for (int n = 0; n < 6; ++n) {
        int p = n * 16 + lr; p = p > 80 ? 80 : p;
        int y = p / 9, xx = p - 9 * y;
        int rb = (y + 1) * 11 + xx + 1;
#pragma unroll
        for (int s = 0; s < 12; ++s) {
            int r, cb;
            if (s < 9)       { r = rb + (s / 3 - 1) * 11 + (s % 3) - 1; cb = lg * 16; }
            else if (s == 9) { r = rb + (lg / 3 - 1) * 11 + (lg % 3) - 1; cb = 64; }
            else if (s == 10){ int tp = lg + 4; r = rb + (tp / 3 - 1) * 11 + (tp % 3) - 1; cb = 64; }
            else             { r = rb + 12; cb = 64; }
            int byte = r * 128 + (cb ^ ((r & 7) << 4));
            bfrag8 bf = *(const bfrag8*)((const char*)xs + byte);
            acc[n] = __builtin_amdgcn_mfma_f32_16x16x32_bf16(a[s], bf, acc[n], 0, 0, 0);
        }
    }
    float* h1b = h1 + (size_t)b * 5184;
    int bucket = (b & 31) << 6;
#pragma unroll
    for (int j = 0; j < 4; ++j) {
        int oo = wv * 16 + lg * 4 + j;
        float bias = b1[oo];
        float ss = 0.f, qq = 0.f;
#pragma unroll
        for (int n = 0; n < 6; ++n) {
            int p = n * 16 + lr;
            float v = fmaxf(acc[n][j] + bias, 0.f);
            if (p < 81) { h1b[oo * 81 + p] = v; ss += v; qq += v * v; }
        }
#pragma unroll
        for (int off = 1; off < 16; off <<= 1) { ss += __shfl_xor(ss, off); qq += __shfl_xor(qq, off); }
        if (lr == 0) { atomicAdd(&sum1[bucket + oo], ss); atomicAdd(&sq1[bucket + oo], qq); }
    }
}

// ---------------- BN finalize (sums 32 replicated buckets) --------------------
__global__ void bn_finalize(const float* __restrict__ sums, const float* __restrict__ sqs,
                            const float* __restrict__ gamma, const float* __restrict__ beta,
                            float* __restrict__ scale, float* __restrict__ shift) {
    int t = threadIdx.x;   // 64
    float s = 0.f, q = 0.f;
#pragma unroll
    for (int r = 0; r < 32; ++r) { s += sums[(r << 6) + t]; q += sqs[(r << 6) + t]; }
    float m = s / (float)NPIX;
    float v = q / (float)NPIX - m * m;
    float sc = gamma[t] * (1.f / sqrtf(v + 1e-5f));
    scale[t] = sc;
    shift[t] = beta[t] - m * sc;
}

// ---------------- BN apply (final output) -------------------------------------
__global__ void bn_apply(float* __restrict__ data, const float* __restrict__ scale,
                         const float* __restrict__ shift, int n, int writeProb,
                         float* __restrict__ dout) {
    int i = blockIdx.x * blockDim.x + threadIdx.x;
    if (writeProb && i == 0) dout[0] = 0.5f;
    for (; i < n; i += gridDim.x * blockDim.x) {
        int c = (i / 81) & 63;
        data[i] = data[i] * scale[c] + shift[c];
    }
}

// ---------------- offset(18) + mask(9, sigmoid) conv, MFMA --------------------
__global__ __launch_bounds__(256) void offmask_mfma(
        const float* __restrict__ h1, const unsigned short* __restrict__ wcm,
        const float* __restrict__ bo, const float* __restrict__ bm,
        const float* __restrict__ scale1, const float* __restrict__ shift1,
        float* __restrict__ dout, float* __restrict__ maskbuf) {
    __shared__ float hsh[5184];
    __shared__ short xs[128 * 64];   // padded swizzled bf16 post-BN image
    __shared__ float sc[64], sh[64];
    int b = blockIdx.x, t = threadIdx.x;
    for (int i = t; i < 4096; i += 256) ((unsigned*)xs)[i] = 0u;
    if (t < 128) { if (t < 64) sc[t] = scale1[t]; else sh[t - 64] = shift1[t - 64]; }
    const float* hb = h1 + (size_t)b * 5184;
    for (int i = t; i < 1296; i += 256) ((float4*)hsh)[i] = ((const float4*)hb)[i];
    __syncthreads();
    for (int i = t; i < 5184; i += 256) {
        int p = i >> 6, c = i & 63;
        float v = hsh[c * 81 + p] * sc[c] + sh[c];
        int y = p / 9, xx = p - 9 * y;
        int r = (y + 1) * 11 + xx + 1;
        int byte = r * 128 + ((c * 2) ^ ((r & 7) << 4));
        xs[byte >> 1] = (short)f2bf(v);
    }
    __syncthreads();
    int lane = t & 63, wv = t >> 6, lg = lane >> 4, lr = lane & 15;
    int mt = wv >> 1, nh = (wv & 1) * 3;
    int ocr = mt * 16 + lr;
    bfrag8 a[18];
#pragma unroll
    for (int s = 0; s < 18; ++s)
        a[s] = *(const bfrag8*)&wcm[(s * 32 + ocr) * 32 + lg * 8];
    floatx4 acc[3];
#pragma unroll
    for (int n = 0; n < 3; ++n) acc[n] = (floatx4)0.f;
#pragma unroll
    for (int ni = 0; ni < 3; ++ni) {
        int p = (nh + ni) * 16 + lr; p = p > 80 ? 80 : p;
        int y = p / 9, xx = p - 9 * y;
        int rb = (y + 1) * 11 + xx + 1;
#pragma unroll
        for (int s = 0; s < 18; ++s) {
            int tap = s >> 1, ch = s & 1;
            int r = rb + (tap / 3 - 1) * 11 + (tap % 3) - 1;
            int byte = r * 128 + ((ch * 64 + lg * 16) ^ ((r & 7) << 4));
            bfrag8 bf = *(const bfrag8*)((const char*)xs + byte);
            acc[ni] = __builtin_amdgcn_mfma_f32_16x16x32_bf16(a[s], bf, acc[ni], 0, 0, 0);
        }
    }
#pragma unroll
    for (int j = 0; j < 4; ++j) {
        int oc = mt * 16 + lg * 4 + j;
        if (oc < 18) {
            float bias = bo[oc];
            float* ob = dout + OUT_OFF_BASE + (size_t)b * 1458 + oc * 81;
#pragma unroll
            for (int ni = 0; ni < 3; ++ni) {
                int p = (nh + ni) * 16 + lr;
                if (p < 81) ob[p] = acc[ni][j] + bias;
            }
        } else if (oc < 27) {
            float bias = bm[oc - 18];
            float* mb = maskbuf + (size_t)b * 729 + (oc - 18) * 81;
#pragma unroll
            for (int ni = 0; ni < 3; ++ni) {
                int p = (nh + ni) * 16 + lr;
                if (p < 81) { float v = acc[ni][j] + bias; mb[p] = 1.f / (1.f + expf(-v)); }
            }
        }
    }
}

// ---------------- deformable conv (MFMA, single-buf vt, 4 blocks/CU) -----------
// LDS 38.9KB: hsh f32 [q][256B] 8B-XOR swz (20736) + bwt uint2 (5832) +
// bix u8x4 (2916) + vt single [81][128B] 16B-XOR swz (10368). No misc LDS.
// A-weights in regs; 18 barriers/block; cross-block TLP (4 blocks/CU) hides them.
__global__ __launch_bounds__(256) void deform_mfma(
        const float* __restrict__ h1, const unsigned short* __restrict__ wdt16,
        const float* __restrict__ maskbuf, const float* __restrict__ bd,
        const float* __restrict__ scale1, const float* __restrict__ shift1,
        float* __restrict__ dout, float* __restrict__ sum2, float* __restrict__ sq2) {
    __shared__ float    hsh[81 * 64];    // byte: q*256 + ((c*4) ^ ((q&31)<<3))
    __shared__ uint2    bwt[729];        // packed bf16 bilinear weights
    __shared__ unsigned bix[729];        // 4x u8 corner q-indices
    __shared__ short    vt[81 * 64];     // byte: p*128 + ((c*2) ^ ((p&7)<<4))

    int b = blockIdx.x, t = threadIdx.x;
    int lane = t & 63, wv = t >> 6, lg = lane >> 4, lr = lane & 15;

    // ---- A fragments from L2-hot global, issued first (72 VGPRs)
    int o = wv * 16 + lr;
    bfrag8 a[18];
#pragma unroll
    for (int s = 0; s < 18; ++s) {
        int k = s >> 1, ks = s & 1;
        a[s] = *(const bfrag8*)&wdt16[(k * 64 + o) * 64 + ks * 32 + lg * 8];
    }

    // ---- stage h: [q][c] f32, swizzled; BN1 folded (scale/shift L1-hot global)
    const float* hb = h1 + (size_t)b * 5184;
    for (int i = t; i < 5184; i += 256) {
        int c = i / 81, q = i - c * 81;
        float v = hb[i] * scale1[c] + shift1[c];
        *(float*)((char*)hsh + q * 256 + ((c * 4) ^ ((q & 31) << 3))) = v;
    }

    // ---- bilinear params once per (tap,pixel)
    const float* goff = dout + OUT_OFF_BASE + (size_t)b * 1458;
    const float* gmsk = maskbuf + (size_t)b * 729;
    for (int i = t; i < 729; i += 256) {
        int k = i / 81, p = i - k * 81;
        float dy = goff[(2 * k) * 81 + p];
        float dx = goff[(2 * k + 1) * 81 + p];
        float m  = gmsk[i];
        int y = p / 9, xx = p - y * 9;
        float py = dy + (float)(y + k / 3 - 1);
        float px = dx + (float)(xx + (k % 3) - 1);
        float fy = floorf(py), fx = floorf(px);
        float ly = py - fy, lx = px - fx;
        int y0 = (int)fy, x0 = (int)fx;
        int y1 = y0 + 1, x1 = x0 + 1;
        bool vy0 = (y0 >= 0) & (y0 < 9), vy1 = (y1 >= 0) & (y1 < 9);
        bool vx0 = (x0 >= 0) & (x0 < 9), vx1 = (x1 >= 0) & (x1 < 9);
        float w00 = (vy0 && vx0) ? m * (1.f - ly) * (1.f - lx) : 0.f;
        float w01 = (vy0 && vx1) ? m * (1.f - ly) * lx : 0.f;
        float w10 = (vy1 && vx0) ? m * ly * (1.f - lx) : 0.f;
        float w11 = (vy1 && vx1) ? m * ly * lx : 0.f;
        int yc0 = min(max(y0, 0), 8), yc1 = min(max(y1, 0), 8);
        int xc0 = min(max(x0, 0), 8), xc1 = min(max(x1, 0), 8);
        unsigned q00 = yc0 * 9 + xc0, q01 = yc0 * 9 + xc1;
        unsigned q10 = yc1 * 9 + xc0, q11 = yc1 * 9 + xc1;
        bwt[i] = make_uint2((unsigned)f2bf(w00) | ((unsigned)f2bf(w01) << 16),
                            (unsigned)f2bf(w10) | ((unsigned)f2bf(w11) << 16));
        bix[i] = q00 | (q01 << 8) | (q10 << 16) | (q11 << 24);
    }
    __syncthreads();

    // ---- fill tap kk into vt: 81p x 32 c-pairs = 2592 items (10 full + 1 partial)
    auto stage_tap = [&](int kk) {
        int kbase = kk * 81;
        char* vb = (char*)vt;
        const char* hc = (const char*)hsh;
        auto S = [](unsigned q) { return (q << 8) | ((q & 31u) << 3); };
#pragma unroll
        for (int j = 0; j < 11; ++j) {
            if (j == 10 && t >= 32) break;
            int i = t + j * 256;
            int c2 = i & 31, p = i >> 5;           // p in 0..80
            uint2 bw = bwt[kbase + p];
            unsigned ix = bix[kbase + p];
            float w00 = bfhi2f(bw.x << 16), w01 = bfhi2f(bw.x & 0xffff0000u);
            float w10 = bfhi2f(bw.y << 16), w11 = bfhi2f(bw.y & 0xffff0000u);
            int c8 = c2 * 8;
            float2 v00 = *(const float2*)(hc + (S(ix & 255u) ^ c8));
            float2 v01 = *(const float2*)(hc + (S((ix >> 8) & 255u) ^ c8));
            float2 v10 = *(const float2*)(hc + (S((ix >> 16) & 255u) ^ c8));
            float2 v11 = *(const float2*)(hc + (S(ix >> 24) ^ c8));
            float s0 = w00 * v00.x + w01 * v01.x + w10 * v10.x + w11 * v11.x;
            float s1 = w00 * v00.y + w01 * v01.y + w10 * v10.y + w11 * v11.y;
            unsigned pk;
            asm("v_cvt_pk_bf16_f32 %0, %1, %2" : "=v"(pk) : "v"(s0), "v"(s1));
            *(unsigned*)(vb + p * 128 + ((c2 * 4) ^ ((p & 7) << 4))) = pk;
        }
    };

    floatx4 acc[6];
#pragma unroll
    for (int n = 0; n < 6; ++n) acc[n] = (floatx4)0.f;
    int rowb[6], swzn[6];
#pragma unroll
    for (int n = 0; n < 6; ++n) {
        int row = n * 16 + lr; row = row > 80 ? 80 : row;
        rowb[n] = row * 128;
        swzn[n] = (row & 7) << 4;
    }

#pragma unroll
    for (int k = 0; k < 9; ++k) {
        stage_tap(k);
        __syncthreads();                       // fill visible to all waves
        const char* vb = (const char*)vt;
#pragma unroll
        for (int n = 0; n < 6; ++n) {
            bfrag8 b0 = *(const bfrag8*)(vb + rowb[n] + ((lg * 16) ^ swzn[n]));
            bfrag8 b1 = *(const bfrag8*)(vb + rowb[n] + ((64 + lg * 16) ^ swzn[n]));
            acc[n] = __builtin_amdgcn_mfma_f32_16x16x32_bf16(a[2 * k], b0, acc[n], 0, 0, 0);
            acc[n] = __builtin_amdgcn_mfma_f32_16x16x32_bf16(a[2 * k + 1], b1, acc[n], 0, 0, 0);
        }
        if (k < 8) __syncthreads();            // all reads done before next fill
    }

    // ---- epilogue: bias, pre-BN output, BN2 stats (replicated buckets)
    float* outb = dout + OUT_H_BASE + (size_t)b * 5184;
    int bucket = (b & 31) << 6;
#pragma unroll
    for (int j = 0; j < 4; ++j) {
        int oo = wv * 16 + lg * 4 + j;
        float bias = bd[oo];
        float ss = 0.f, qq = 0.f;
#pragma unroll
        for (int n = 0; n < 6; ++n) {
            int p = n * 16 + lr;
            float v = acc[n][j] + bias;
            if (p < 81) { outb[oo * 81 + p] = v; ss += v; qq += v * v; }
        }
#pragma unroll
        for (int off = 1; off < 16; off <<= 1) {
            ss += __shfl_xor(ss, off);
            qq += __shfl_xor(qq, off);
        }
        if (lr == 0) { atomicAdd(&sum2[bucket + oo], ss); atomicAdd(&sq2[bucket + oo], qq); }
    }
}

// ---------------- launch -------------------------------------------------------
extern "C" void kernel_launch(void* const* d_in, const int* in_sizes, int n_in,
                              void* d_out, int out_size, void* d_ws, size_t ws_size,
                              hipStream_t stream) {
    const float* x   = (const float*)d_in[0];
    const float* w1  = (const float*)d_in[1];
    const float* b1  = (const float*)d_in[2];
    const float* g1  = (const float*)d_in[3];
    const float* be1 = (const float*)d_in[4];
    const float* wo  = (const float*)d_in[5];
    const float* bo  = (const float*)d_in[6];
    const float* wm  = (const float*)d_in[7];
    const float* bm  = (const float*)d_in[8];
    const float* wd  = (const float*)d_in[9];
    const float* bd  = (const float*)d_in[10];
    const float* g2  = (const float*)d_in[11];
    const float* be2 = (const float*)d_in[12];
    float* dout = (float*)d_out;
    float* ws   = (float*)d_ws;

    float* h1    = ws + WS_H1;
    float* maskb = ws + WS_MASK;
    const unsigned short* wdt16 = (const unsigned short*)(ws + WS_WDT);
    const unsigned short* w1m   = (const unsigned short*)(ws + WS_W1M);
    const unsigned short* wcm   = (const unsigned short*)(ws + WS_WCM);
    float* stats = ws + WS_STATS;
    float* sum1 = stats,        *sq1 = stats + 2048;
    float* sum2 = stats + 4096, *sq2 = stats + 6144;
    float* scale1 = stats + 8192, *shift1 = stats + 8256;
    float* scale2 = stats + 8320, *shift2 = stats + 8384;

    // zero the replicated BN accumulators (ws is NOT re-poisoned between replays)
    hipMemsetAsync(stats, 0, 8192 * sizeof(float), stream);

    prep_weights<<<312, 256, 0, stream>>>(w1, wo, wm, wd, ws);
    conv1_mfma<<<BATCH, 256, 0, stream>>>(x, b1, w1m, h1, sum1, sq1);
    bn_finalize<<<1, 64, 0, stream>>>(sum1, sq1, g1, be1, scale1, shift1);
    offmask_mfma<<<BATCH, 256, 0, stream>>>(h1, wcm, bo, bm, scale1, shift1, dout, maskb);
    deform_mfma<<<BATCH, 256, 0, stream>>>(h1, wdt16, maskb, bd, scale1, shift1, dout, sum2, sq2);
    bn_finalize<<<1, 64, 0, stream>>>(sum2, sq2, g2, be2, scale2, shift2);
    bn_apply<<<2048, 256, 0, stream>>>(dout + OUT_H_BASE, scale2, shift2, BATCH * 5184, 1, dout);
}

// Round 8
// 162.652 us; speedup vs baseline: 4.2736x; 1.0014x over previous
//
#include <hip/hip_runtime.h>
#include <hip/hip_bf16.h>

// Problem constants
#define BATCH   2048
#define HW      81          // 9x9
#define CIN     39
#define NPIX    (BATCH*HW)  // 165888

// ws layout (float offsets)
#define WS_H1     0              // 10,616,832 floats  (B,64,81)  PRE-BN h
#define WS_MASK   10616832       // 1,492,992 floats   (B,9,81)
#define WS_WDT    12109824       // 36,864 ushort bf16 [k][o][c]   (18,432 floats)
#define WS_W1M    12128256       // 24,576 ushort bf16 [12][64][32] (12,288 floats)
#define WS_WCM    12140544       // 18,432 ushort bf16 [18][32][32] (9,216 floats)
#define WS_STATS  12149760       // 8448 floats: sum1[2048],sq1[2048],sum2[2048],sq2[2048],
                                 //              scale1,shift1,scale2,shift2 (64 each)

#define OUT_OFF_BASE 1
#define OUT_H_BASE   (1 + BATCH*18*81)   // 2985985

typedef __attribute__((ext_vector_type(8))) short bfrag8;
typedef __attribute__((ext_vector_type(4))) float floatx4;

__device__ __forceinline__ unsigned short f2bf(float f) {
    unsigned u = __builtin_bit_cast(unsigned, f);
    u += 0x7FFFu + ((u >> 16) & 1u);       // round-to-nearest-even
    return (unsigned short)(u >> 16);
}
__device__ __forceinline__ float bfhi2f(unsigned hi16) {   // hi16 already in bits 31..16
    return __builtin_bit_cast(float, hi16);
}

// ---------------- weight prep: fragment-ready bf16 layouts --------------------
__global__ void prep_weights(const float* __restrict__ w1, const float* __restrict__ wo,
                             const float* __restrict__ wm, const float* __restrict__ wd,
                             float* __restrict__ ws) {
    int idx = blockIdx.x * 256 + threadIdx.x;
    unsigned short* w1m = (unsigned short*)(ws + WS_W1M);
    unsigned short* wcm = (unsigned short*)(ws + WS_WCM);
    unsigned short* wdt16 = (unsigned short*)(ws + WS_WDT);
    if (idx < 24576) {
        int kk = idx & 31, o = (idx >> 5) & 63, s = idx >> 11;
        int tap, c; bool ok = true;
        if (s < 9)       { tap = s;             c = kk; }
        else if (s == 9) { tap = kk >> 3;       c = 32 + (kk & 7); }
        else if (s == 10){ tap = 4 + (kk >> 3); c = 32 + (kk & 7); }
        else             { tap = 8;             c = 32 + (kk & 7); ok = (kk < 8); }
        float v = (ok && c < CIN) ? w1[(o * CIN + c) * 9 + tap] : 0.f;
        w1m[idx] = f2bf(v);
        return;
    }
    int j = idx - 24576;
    if (j >= 0 && j < 18432) {
        int kk = j & 31, oc = (j >> 5) & 31, s = j >> 10;
        int tap = s >> 1, c = (s & 1) * 32 + kk;
        float v = 0.f;
        if (oc < 18)      v = wo[(oc * 64 + c) * 9 + tap];
        else if (oc < 27) v = wm[((oc - 18) * 64 + c) * 9 + tap];
        wcm[j] = f2bf(v);
        return;
    }
    int m = idx - 24576 - 18432;
    if (m >= 0 && m < 36864) {
        int c = m & 63, o = (m >> 6) & 63, k = m >> 12;
        wdt16[m] = f2bf(wd[(o * 64 + c) * 9 + k]);
    }
}

// ---------------- conv1 (39->64) MFMA + ReLU + BN1 stats ----------------------
__global__ __launch_bounds__(256) void conv1_mfma(
        const float* __restrict__ xg, const float* __restrict__ b1,
        const unsigned short* __restrict__ w1m, float* __restrict__ h1,
        float* __restrict__ sum1, float* __restrict__ sq1) {
    __shared__ short xs[128 * 64];   // [r(121)][c(64)] bf16, byte ^= (r&7)<<4
    int b = blockIdx.x, t = threadIdx.x;
    for (int i = t; i < 4096; i += 256) ((unsigned*)xs)[i] = 0u;
    __syncthreads();
    const float* xb = xg + (size_t)b * (HW * CIN);
    for (int i = t; i < HW * CIN; i += 256) {
        int p = i / 39, c = i - 39 * p;
        int y = p / 9, xx = p - 9 * y;
        int r = (y + 1) * 11 + xx + 1;
        int byte = r * 128 + ((c * 2) ^ ((r & 7) << 4));
        xs[byte >> 1] = (short)f2bf(xb[i]);
    }
    __syncthreads();
    int lane = t & 63, wv = t >> 6, lg = lane >> 4, lr = lane & 15;
    int o = wv * 16 + lr;
    bfrag8 a[12];
#pragma unroll
    for (int s = 0; s < 12; ++s)
        a[s] = *(const bfrag8*)&w1m[(s * 64 + o) * 32 + lg * 8];
    floatx4 acc[6];
#pragma unroll
    for (int n = 0; n < 6; ++n) acc[n] = (floatx4)0.f;
#pragma unroll
    for (int n = 0; n < 6; ++n) {
        int p = n * 16 + lr; p = p > 80 ? 80 : p;
        int y = p / 9, xx = p - 9 * y;
        int rb = (y + 1) * 11 + xx + 1;
#pragma unroll
        for (int s = 0; s < 12; ++s) {
            int r, cb;
            if (s < 9)       { r = rb + (s / 3 - 1) * 11 + (s % 3) - 1; cb = lg * 16; }
            else if (s == 9) { r = rb + (lg / 3 - 1) * 11 + (lg % 3) - 1; cb = 64; }
            else if (s == 10){ int tp = lg + 4; r = rb + (tp / 3 - 1) * 11 + (tp % 3) - 1; cb = 64; }
            else             { r = rb + 12; cb = 64; }
            int byte = r * 128 + (cb ^ ((r & 7) << 4));
            bfrag8 bf = *(const bfrag8*)((const char*)xs + byte);
            acc[n] = __builtin_amdgcn_mfma_f32_16x16x32_bf16(a[s], bf, acc[n], 0, 0, 0);
        }
    }
    float* h1b = h1 + (size_t)b * 5184;
    int bucket = (b & 31) << 6;
#pragma unroll
    for (int j = 0; j < 4; ++j) {
        int oo = wv * 16 + lg * 4 + j;
        float bias = b1[oo];
        float ss = 0.f, qq = 0.f;
#pragma unroll
        for (int n = 0; n < 6; ++n) {
            int p = n * 16 + lr;
            float v = fmaxf(acc[n][j] + bias, 0.f);
            if (p < 81) { h1b[oo * 81 + p] = v; ss += v; qq += v * v; }
        }
#pragma unroll
        for (int off = 1; off < 16; off <<= 1) { ss += __shfl_xor(ss, off); qq += __shfl_xor(qq, off); }
        if (lr == 0) { atomicAdd(&sum1[bucket + oo], ss); atomicAdd(&sq1[bucket + oo], qq); }
    }
}

// ---------------- BN finalize (sums 32 replicated buckets) --------------------
__global__ void bn_finalize(const float* __restrict__ sums, const float* __restrict__ sqs,
                            const float* __restrict__ gamma, const float* __restrict__ beta,
                            float* __restrict__ scale, float* __restrict__ shift) {
    int t = threadIdx.x;   // 64
    float s = 0.f, q = 0.f;
#pragma unroll
    for (int r = 0; r < 32; ++r) { s += sums[(r << 6) + t]; q += sqs[(r << 6) + t]; }
    float m = s / (float)NPIX;
    float v = q / (float)NPIX - m * m;
    float sc = gamma[t] * (1.f / sqrtf(v + 1e-5f));
    scale[t] = sc;
    shift[t] = beta[t] - m * sc;
}

// ---------------- BN apply (final output) -------------------------------------
__global__ void bn_apply(float* __restrict__ data, const float* __restrict__ scale,
                         const float* __restrict__ shift, int n, int writeProb,
                         float* __restrict__ dout) {
    int i = blockIdx.x * blockDim.x + threadIdx.x;
    if (writeProb && i == 0) dout[0] = 0.5f;
    for (; i < n; i += gridDim.x * blockDim.x) {
        int c = (i / 81) & 63;
        data[i] = data[i] * scale[c] + shift[c];
    }
}

// ---------------- offset(18) + mask(9, sigmoid) conv, MFMA --------------------
__global__ __launch_bounds__(256) void offmask_mfma(
        const float* __restrict__ h1, const unsigned short* __restrict__ wcm,
        const float* __restrict__ bo, const float* __restrict__ bm,
        const float* __restrict__ scale1, const float* __restrict__ shift1,
        float* __restrict__ dout, float* __restrict__ maskbuf) {
    __shared__ float hsh[5184];
    __shared__ short xs[128 * 64];   // padded swizzled bf16 post-BN image
    __shared__ float sc[64], sh[64];
    int b = blockIdx.x, t = threadIdx.x;
    for (int i = t; i < 4096; i += 256) ((unsigned*)xs)[i] = 0u;
    if (t < 128) { if (t < 64) sc[t] = scale1[t]; else sh[t - 64] = shift1[t - 64]; }
    const float* hb = h1 + (size_t)b * 5184;
    for (int i = t; i < 1296; i += 256) ((float4*)hsh)[i] = ((const float4*)hb)[i];
    __syncthreads();
    for (int i = t; i < 5184; i += 256) {
        int p = i >> 6, c = i & 63;
        float v = hsh[c * 81 + p] * sc[c] + sh[c];
        int y = p / 9, xx = p - 9 * y;
        int r = (y + 1) * 11 + xx + 1;
        int byte = r * 128 + ((c * 2) ^ ((r & 7) << 4));
        xs[byte >> 1] = (short)f2bf(v);
    }
    __syncthreads();
    int lane = t & 63, wv = t >> 6, lg = lane >> 4, lr = lane & 15;
    int mt = wv >> 1, nh = (wv & 1) * 3;
    int ocr = mt * 16 + lr;
    bfrag8 a[18];
#pragma unroll
    for (int s = 0; s < 18; ++s)
        a[s] = *(const bfrag8*)&wcm[(s * 32 + ocr) * 32 + lg * 8];
    floatx4 acc[3];
#pragma unroll
    for (int n = 0; n < 3; ++n) acc[n] = (floatx4)0.f;
#pragma unroll
    for (int ni = 0; ni < 3; ++ni) {
        int p = (nh + ni) * 16 + lr; p = p > 80 ? 80 : p;
        int y = p / 9, xx = p - 9 * y;
        int rb = (y + 1) * 11 + xx + 1;
#pragma unroll
        for (int s = 0; s < 18; ++s) {
            int tap = s >> 1, ch = s & 1;
            int r = rb + (tap / 3 - 1) * 11 + (tap % 3) - 1;
            int byte = r * 128 + ((ch * 64 + lg * 16) ^ ((r & 7) << 4));
            bfrag8 bf = *(const bfrag8*)((const char*)xs + byte);
            acc[ni] = __builtin_amdgcn_mfma_f32_16x16x32_bf16(a[s], bf, acc[ni], 0, 0, 0);
        }
    }
#pragma unroll
    for (int j = 0; j < 4; ++j) {
        int oc = mt * 16 + lg * 4 + j;
        if (oc < 18) {
            float bias = bo[oc];
            float* ob = dout + OUT_OFF_BASE + (size_t)b * 1458 + oc * 81;
#pragma unroll
            for (int ni = 0; ni < 3; ++ni) {
                int p = (nh + ni) * 16 + lr;
                if (p < 81) ob[p] = acc[ni][j] + bias;
            }
        } else if (oc < 27) {
            float bias = bm[oc - 18];
            float* mb = maskbuf + (size_t)b * 729 + (oc - 18) * 81;
#pragma unroll
            for (int ni = 0; ni < 3; ++ni) {
                int p = (nh + ni) * 16 + lr;
                if (p < 81) { float v = acc[ni][j] + bias; mb[p] = 1.f / (1.f + expf(-v)); }
            }
        }
    }
}

// ---------------- deformable conv (MFMA, single-buf vt, 4 blocks/CU) -----------
// Fill re-mapped: slot = p*4 + c-octet (324 slots/tap). Per slot the bilinear
// weights + 4 swizzled corner bases are computed ONCE (was 32x redundant), then
// 8 c-pairs stream via base^(c2*8) b64 reads; results stored as two contiguous
// b128 writes (16B swizzle granularity keeps each 16B run contiguous).
__global__ __launch_bounds__(256) void deform_mfma(
        const float* __restrict__ h1, const unsigned short* __restrict__ wdt16,
        const float* __restrict__ maskbuf, const float* __restrict__ bd,
        const float* __restrict__ scale1, const float* __restrict__ shift1,
        float* __restrict__ dout, float* __restrict__ sum2, float* __restrict__ sq2) {
    __shared__ float    hsh[81 * 64];    // byte: q*256 + ((c*4) ^ ((q&31)<<3))
    __shared__ uint2    bwt[729];        // packed bf16 bilinear weights
    __shared__ unsigned bix[729];        // 4x u8 corner q-indices
    __shared__ short    vt[81 * 64];     // byte: p*128 + ((c*2) ^ ((p&7)<<4))

    int b = blockIdx.x, t = threadIdx.x;
    int lane = t & 63, wv = t >> 6, lg = lane >> 4, lr = lane & 15;

    // ---- A fragments from L2-hot global, issued first (72 VGPRs)
    int o = wv * 16 + lr;
    bfrag8 a[18];
#pragma unroll
    for (int s = 0; s < 18; ++s) {
        int k = s >> 1, ks = s & 1;
        a[s] = *(const bfrag8*)&wdt16[(k * 64 + o) * 64 + ks * 32 + lg * 8];
    }

    // ---- stage h: [q][c] f32, swizzled; BN1 folded (scale/shift L1-hot global)
    const float* hb = h1 + (size_t)b * 5184;
    for (int i = t; i < 5184; i += 256) {
        int c = i / 81, q = i - c * 81;
        float v = hb[i] * scale1[c] + shift1[c];
        *(float*)((char*)hsh + q * 256 + ((c * 4) ^ ((q & 31) << 3))) = v;
    }

    // ---- bilinear params once per (tap,pixel)
    const float* goff = dout + OUT_OFF_BASE + (size_t)b * 1458;
    const float* gmsk = maskbuf + (size_t)b * 729;
    for (int i = t; i < 729; i += 256) {
        int k = i / 81, p = i - k * 81;
        float dy = goff[(2 * k) * 81 + p];
        float dx = goff[(2 * k + 1) * 81 + p];
        float m  = gmsk[i];
        int y = p / 9, xx = p - y * 9;
        float py = dy + (float)(y + k / 3 - 1);
        float px = dx + (float)(xx + (k % 3) - 1);
        float fy = floorf(py), fx = floorf(px);
        float ly = py - fy, lx = px - fx;
        int y0 = (int)fy, x0 = (int)fx;
        int y1 = y0 + 1, x1 = x0 + 1;
        bool vy0 = (y0 >= 0) & (y0 < 9), vy1 = (y1 >= 0) & (y1 < 9);
        bool vx0 = (x0 >= 0) & (x0 < 9), vx1 = (x1 >= 0) & (x1 < 9);
        float w00 = (vy0 && vx0) ? m * (1.f - ly) * (1.f - lx) : 0.f;
        float w01 = (vy0 && vx1) ? m * (1.f - ly) * lx : 0.f;
        float w10 = (vy1 && vx0) ? m * ly * (1.f - lx) : 0.f;
        float w11 = (vy1 && vx1) ? m * ly * lx : 0.f;
        int yc0 = min(max(y0, 0), 8), yc1 = min(max(y1, 0), 8);
        int xc0 = min(max(x0, 0), 8), xc1 = min(max(x1, 0), 8);
        unsigned q00 = yc0 * 9 + xc0, q01 = yc0 * 9 + xc1;
        unsigned q10 = yc1 * 9 + xc0, q11 = yc1 * 9 + xc1;
        bwt[i] = make_uint2((unsigned)f2bf(w00) | ((unsigned)f2bf(w01) << 16),
                            (unsigned)f2bf(w10) | ((unsigned)f2bf(w11) << 16));
        bix[i] = q00 | (q01 << 8) | (q10 << 16) | (q11 << 24);
    }
    __syncthreads();

    // ---- fill tap kk into vt: 324 slots = (81 p) x (4 c-octets)
    auto stage_tap = [&](int kk) {
        int kbase = kk * 81;
        char* vb = (char*)vt;
        const char* hc = (const char*)hsh;
#pragma unroll
        for (int j = 0; j < 2; ++j) {
            int s = t + j * 256;
            if (j == 1 && s >= 324) break;
            int g = s & 3, p = s >> 2;
            uint2 bw = bwt[kbase + p];
            unsigned ix = bix[kbase + p];
            float w00 = bfhi2f(bw.x << 16), w01 = bfhi2f(bw.x & 0xffff0000u);
            float w10 = bfhi2f(bw.y << 16), w11 = bfhi2f(bw.y & 0xffff0000u);
            unsigned q00 = ix & 255u, q01 = (ix >> 8) & 255u;
            unsigned q10 = (ix >> 16) & 255u, q11 = ix >> 24;
            int b00 = (int)((q00 << 8) | ((q00 & 31u) << 3));
            int b01 = (int)((q01 << 8) | ((q01 & 31u) << 3));
            int b10 = (int)((q10 << 8) | ((q10 & 31u) << 3));
            int b11 = (int)((q11 << 8) | ((q11 & 31u) << 3));
            unsigned res[8];
#pragma unroll
            for (int i = 0; i < 8; ++i) {
                int c8 = (g * 8 + i) * 8;       // byte offset of float2 pair
                float2 v00 = *(const float2*)(hc + (b00 ^ c8));
                float2 v01 = *(const float2*)(hc + (b01 ^ c8));
                float2 v10 = *(const float2*)(hc + (b10 ^ c8));
                float2 v11 = *(const float2*)(hc + (b11 ^ c8));
                float s0 = w00 * v00.x + w01 * v01.x + w10 * v10.x + w11 * v11.x;
                float s1 = w00 * v00.y + w01 * v01.y + w10 * v10.y + w11 * v11.y;
                unsigned pk;
                asm("v_cvt_pk_bf16_f32 %0, %1, %2" : "=v"(pk) : "v"(s0), "v"(s1));
                res[i] = pk;
            }
            int swz = (p & 7) << 4;
            char* row = vb + p * 128;
            *(uint4*)(row + ((32 * g) ^ swz)) = make_uint4(res[0], res[1], res[2], res[3]);
            *(uint4*)(row + ((32 * g + 16) ^ swz)) = make_uint4(res[4], res[5], res[6], res[7]);
        }
    };

    floatx4 acc[6];
#pragma unroll
    for (int n = 0; n < 6; ++n) acc[n] = (floatx4)0.f;
    int rowb[6], swzn[6];
#pragma unroll
    for (int n = 0; n < 6; ++n) {
        int row = n * 16 + lr; row = row > 80 ? 80 : row;
        rowb[n] = row * 128;
        swzn[n] = (row & 7) << 4;
    }

#pragma unroll
    for (int k = 0; k < 9; ++k) {
        stage_tap(k);
        __syncthreads();                       // fill visible to all waves
        const char* vb = (const char*)vt;
#pragma unroll
        for (int n = 0; n < 6; ++n) {
            bfrag8 b0 = *(const bfrag8*)(vb + rowb[n] + ((lg * 16) ^ swzn[n]));
            bfrag8 b1 = *(const bfrag8*)(vb + rowb[n] + ((64 + lg * 16) ^ swzn[n]));
            acc[n] = __builtin_amdgcn_mfma_f32_16x16x32_bf16(a[2 * k], b0, acc[n], 0, 0, 0);
            acc[n] = __builtin_amdgcn_mfma_f32_16x16x32_bf16(a[2 * k + 1], b1, acc[n], 0, 0, 0);
        }
        if (k < 8) __syncthreads();            // all reads done before next fill
    }

    // ---- epilogue: bias, pre-BN output, BN2 stats (replicated buckets)
    float* outb = dout + OUT_H_BASE + (size_t)b * 5184;
    int bucket = (b & 31) << 6;
#pragma unroll
    for (int j = 0; j < 4; ++j) {
        int oo = wv * 16 + lg * 4 + j;
        float bias = bd[oo];
        float ss = 0.f, qq = 0.f;
#pragma unroll
        for (int n = 0; n < 6; ++n) {
            int p = n * 16 + lr;
            float v = acc[n][j] + bias;
            if (p < 81) { outb[oo * 81 + p] = v; ss += v; qq += v * v; }
        }
#pragma unroll
        for (int off = 1; off < 16; off <<= 1) {
            ss += __shfl_xor(ss, off);
            qq += __shfl_xor(qq, off);
        }
        if (lr == 0) { atomicAdd(&sum2[bucket + oo], ss); atomicAdd(&sq2[bucket + oo], qq); }
    }
}

// ---------------- launch -------------------------------------------------------
extern "C" void kernel_launch(void* const* d_in, const int* in_sizes, int n_in,
                              void* d_out, int out_size, void* d_ws, size_t ws_size,
                              hipStream_t stream) {
    const float* x   = (const float*)d_in[0];
    const float* w1  = (const float*)d_in[1];
    const float* b1  = (const float*)d_in[2];
    const float* g1  = (const float*)d_in[3];
    const float* be1 = (const float*)d_in[4];
    const float* wo  = (const float*)d_in[5];
    const float* bo  = (const float*)d_in[6];
    const float* wm  = (const float*)d_in[7];
    const float* bm  = (const float*)d_in[8];
    const float* wd  = (const float*)d_in[9];
    const float* bd  = (const float*)d_in[10];
    const float* g2  = (const float*)d_in[11];
    const float* be2 = (const float*)d_in[12];
    float* dout = (float*)d_out;
    float* ws   = (float*)d_ws;

    float* h1    = ws + WS_H1;
    float* maskb = ws + WS_MASK;
    const unsigned short* wdt16 = (const unsigned short*)(ws + WS_WDT);
    const unsigned short* w1m   = (const unsigned short*)(ws + WS_W1M);
    const unsigned short* wcm   = (const unsigned short*)(ws + WS_WCM);
    float* stats = ws + WS_STATS;
    float* sum1 = stats,        *sq1 = stats + 2048;
    float* sum2 = stats + 4096, *sq2 = stats + 6144;
    float* scale1 = stats + 8192, *shift1 = stats + 8256;
    float* scale2 = stats + 8320, *shift2 = stats + 8384;

    // zero the replicated BN accumulators (ws is NOT re-poisoned between replays)
    hipMemsetAsync(stats, 0, 8192 * sizeof(float), stream);

    prep_weights<<<312, 256, 0, stream>>>(w1, wo, wm, wd, ws);
    conv1_mfma<<<BATCH, 256, 0, stream>>>(x, b1, w1m, h1, sum1, sq1);
    bn_finalize<<<1, 64, 0, stream>>>(sum1, sq1, g1, be1, scale1, shift1);
    offmask_mfma<<<BATCH, 256, 0, stream>>>(h1, wcm, bo, bm, scale1, shift1, dout, maskb);
    deform_mfma<<<BATCH, 256, 0, stream>>>(h1, wdt16, maskb, bd, scale1, shift1, dout, sum2, sq2);
    bn_finalize<<<1, 64, 0, stream>>>(sum2, sq2, g2, be2, scale2, shift2);
    bn_apply<<<2048, 256, 0, stream>>>(dout + OUT_H_BASE, scale2, shift2, BATCH * 5184, 1, dout);
}

// Round 9
// 151.131 us; speedup vs baseline: 4.5994x; 1.0762x over previous
//
#include <hip/hip_runtime.h>
#include <hip/hip_bf16.h>

// Problem constants
#define BATCH   2048
#define HW      81          // 9x9
#define CIN     39
#define NPIX    (BATCH*HW)  // 165888

// ws layout (float offsets)
#define WS_H1     0              // 10,616,832 floats  (B,64,81)  PRE-BN h
#define WS_WDT    12109824       // 36,864 ushort bf16 [k][o][c]   (18,432 floats)
#define WS_W1M    12128256       // 24,576 ushort bf16 [12][64][32] (12,288 floats)
#define WS_WCM    12140544       // 18,432 ushort bf16 [18][32][32] (9,216 floats)
#define WS_STATS  12149760       // 8448 floats: sum1[2048],sq1[2048],sum2[2048],sq2[2048],
                                 //              scale1,shift1,scale2,shift2 (64 each)

#define OUT_OFF_BASE 1
#define OUT_H_BASE   (1 + BATCH*18*81)   // 2985985

typedef __attribute__((ext_vector_type(8))) short bfrag8;
typedef __attribute__((ext_vector_type(4))) float floatx4;

__device__ __forceinline__ unsigned short f2bf(float f) {
    unsigned u = __builtin_bit_cast(unsigned, f);
    u += 0x7FFFu + ((u >> 16) & 1u);       // round-to-nearest-even
    return (unsigned short)(u >> 16);
}
__device__ __forceinline__ float bfhi2f(unsigned hi16) {   // hi16 already in bits 31..16
    return __builtin_bit_cast(float, hi16);
}

// ---------------- weight prep: fragment-ready bf16 layouts --------------------
__global__ void prep_weights(const float* __restrict__ w1, const float* __restrict__ wo,
                             const float* __restrict__ wm, const float* __restrict__ wd,
                             float* __restrict__ ws) {
    int idx = blockIdx.x * 256 + threadIdx.x;
    unsigned short* w1m = (unsigned short*)(ws + WS_W1M);
    unsigned short* wcm = (unsigned short*)(ws + WS_WCM);
    unsigned short* wdt16 = (unsigned short*)(ws + WS_WDT);
    if (idx < 24576) {
        int kk = idx & 31, o = (idx >> 5) & 63, s = idx >> 11;
        int tap, c; bool ok = true;
        if (s < 9)       { tap = s;             c = kk; }
        else if (s == 9) { tap = kk >> 3;       c = 32 + (kk & 7); }
        else if (s == 10){ tap = 4 + (kk >> 3); c = 32 + (kk & 7); }
        else             { tap = 8;             c = 32 + (kk & 7); ok = (kk < 8); }
        float v = (ok && c < CIN) ? w1[(o * CIN + c) * 9 + tap] : 0.f;
        w1m[idx] = f2bf(v);
        return;
    }
    int j = idx - 24576;
    if (j >= 0 && j < 18432) {
        int kk = j & 31, oc = (j >> 5) & 31, s = j >> 10;
        int tap = s >> 1, c = (s & 1) * 32 + kk;
        float v = 0.f;
        if (oc < 18)      v = wo[(oc * 64 + c) * 9 + tap];
        else if (oc < 27) v = wm[((oc - 18) * 64 + c) * 9 + tap];
        wcm[j] = f2bf(v);
        return;
    }
    int m = idx - 24576 - 18432;
    if (m >= 0 && m < 36864) {
        int c = m & 63, o = (m >> 6) & 63, k = m >> 12;
        wdt16[m] = f2bf(wd[(o * 64 + c) * 9 + k]);
    }
}

// ---------------- conv1 (39->64) MFMA + ReLU + BN1 stats ----------------------
__global__ __launch_bounds__(256) void conv1_mfma(
        const float* __restrict__ xg, const float* __restrict__ b1,
        const unsigned short* __restrict__ w1m, float* __restrict__ h1,
        float* __restrict__ sum1, float* __restrict__ sq1) {
    __shared__ short xs[128 * 64];   // [r(121)][c(64)] bf16, byte ^= (r&7)<<4
    int b = blockIdx.x, t = threadIdx.x;
    for (int i = t; i < 4096; i += 256) ((unsigned*)xs)[i] = 0u;
    __syncthreads();
    const float* xb = xg + (size_t)b * (HW * CIN);
    for (int i = t; i < HW * CIN; i += 256) {
        int p = i / 39, c = i - 39 * p;
        int y = p / 9, xx = p - 9 * y;
        int r = (y + 1) * 11 + xx + 1;
        int byte = r * 128 + ((c * 2) ^ ((r & 7) << 4));
        xs[byte >> 1] = (short)f2bf(xb[i]);
    }
    __syncthreads();
    int lane = t & 63, wv = t >> 6, lg = lane >> 4, lr = lane & 15;
    int o = wv * 16 + lr;
    bfrag8 a[12];
#pragma unroll
    for (int s = 0; s < 12; ++s)
        a[s] = *(const bfrag8*)&w1m[(s * 64 + o) * 32 + lg * 8];
    floatx4 acc[6];
#pragma unroll
    for (int n = 0; n < 6; ++n) acc[n] = (floatx4)0.f;
#pragma unroll
    for (int n = 0; n < 6; ++n) {
        int p = n * 16 + lr; p = p > 80 ? 80 : p;
        int y = p / 9, xx = p - 9 * y;
        int rb = (y + 1) * 11 + xx + 1;
#pragma unroll
        for (int s = 0; s < 12; ++s) {
            int r, cb;
            if (s < 9)       { r = rb + (s / 3 - 1) * 11 + (s % 3) - 1; cb = lg * 16; }
            else if (s == 9) { r = rb + (lg / 3 - 1) * 11 + (lg % 3) - 1; cb = 64; }
            else if (s == 10){ int tp = lg + 4; r = rb + (tp / 3 - 1) * 11 + (tp % 3) - 1; cb = 64; }
            else             { r = rb + 12; cb = 64; }
            int byte = r * 128 + (cb ^ ((r & 7) << 4));
            bfrag8 bf = *(const bfrag8*)((const char*)xs + byte);
            acc[n] = __builtin_amdgcn_mfma_f32_16x16x32_bf16(a[s], bf, acc[n], 0, 0, 0);
        }
    }
    float* h1b = h1 + (size_t)b * 5184;
    int bucket = (b & 31) << 6;
#pragma unroll
    for (int j = 0; j < 4; ++j) {
        int oo = wv * 16 + lg * 4 + j;
        float bias = b1[oo];
        float ss = 0.f, qq = 0.f;
#pragma unroll
        for (int n = 0; n < 6; ++n) {
            int p = n * 16 + lr;
            float v = fmaxf(acc[n][j] + bias, 0.f);
            if (p < 81) { h1b[oo * 81 + p] = v; ss += v; qq += v * v; }
        }
#pragma unroll
        for (int off = 1; off < 16; off <<= 1) { ss += __shfl_xor(ss, off); qq += __shfl_xor(qq, off); }
        if (lr == 0) { atomicAdd(&sum1[bucket + oo], ss); atomicAdd(&sq1[bucket + oo], qq); }
    }
}

// ---------------- BN finalize (sums 32 replicated buckets) --------------------
__global__ void bn_finalize(const float* __restrict__ sums, const float* __restrict__ sqs,
                            const float* __restrict__ gamma, const float* __restrict__ beta,
                            float* __restrict__ scale, float* __restrict__ shift) {
    int t = threadIdx.x;   // 64
    float s = 0.f, q = 0.f;
#pragma unroll
    for (int r = 0; r < 32; ++r) { s += sums[(r << 6) + t]; q += sqs[(r << 6) + t]; }
    float m = s / (float)NPIX;
    float v = q / (float)NPIX - m * m;
    float sc = gamma[t] * (1.f / sqrtf(v + 1e-5f));
    scale[t] = sc;
    shift[t] = beta[t] - m * sc;
}

// ---------------- BN apply (final output) -------------------------------------
__global__ void bn_apply(float* __restrict__ data, const float* __restrict__ scale,
                         const float* __restrict__ shift, int n, int writeProb,
                         float* __restrict__ dout) {
    int i = blockIdx.x * blockDim.x + threadIdx.x;
    if (writeProb && i == 0) dout[0] = 0.5f;
    for (; i < n; i += gridDim.x * blockDim.x) {
        int c = (i / 81) & 63;
        data[i] = data[i] * scale[c] + shift[c];
    }
}

// ---------------- FUSED offset/mask conv + deformable conv (MFMA) --------------
// One block per image. LDS 39.9KB -> 4 blocks/CU:
//   hsh   [0,20736)      : f32 [q][256B], byte q*256 + ((c*4)^((q&31)<<3))
//   bwt   [20736,26568)  : uint2[729] packed bf16 bilinear weights
//   bix   [26568,29484)  : uint[729] 4x u8 corner q-indices
//   V     [29488,39856)  : P1-P2: offsets f32[1458] + mask f32[729]
//                          fills:  vt bf16 [p][128B], byte p*128 + ((c*2)^((p&7)<<4))
// offmask B-fragments generated on-the-fly from hsh (cvt_pk, RNE == f2bf).
__global__ __launch_bounds__(256, 4) void offdeform_mfma(
        const float* __restrict__ h1, const unsigned short* __restrict__ wcm,
        const unsigned short* __restrict__ wdt16,
        const float* __restrict__ bo, const float* __restrict__ bm,
        const float* __restrict__ bd,
        const float* __restrict__ scale1, const float* __restrict__ shift1,
        float* __restrict__ dout, float* __restrict__ sum2, float* __restrict__ sq2) {
    __shared__ __align__(16) char L[39856];
    float*    hsh = (float*)L;
    uint2*    bwt = (uint2*)(L + 20736);
    unsigned* bix = (unsigned*)(L + 26568);
    float*    om  = (float*)(L + 29488);       // offsets [1458]
    float*    omm = om + 1458;                 // mask [729]
    char*     vtb = L + 29488;                 // vt region (after P2)

    int b = blockIdx.x, t = threadIdx.x;
    int lane = t & 63, wv = t >> 6, lg = lane >> 4, lr = lane & 15;

    // ---- P0: stage h (f32 post-BN, swizzled)
    const float* hb = h1 + (size_t)b * 5184;
    for (int i = t; i < 5184; i += 256) {
        int c = i / 81, q = i - c * 81;
        float v = hb[i] * scale1[c] + shift1[c];
        *(float*)((char*)hsh + q * 256 + ((c * 4) ^ ((q & 31) << 3))) = v;
    }
    __syncthreads();

    // ---- P1: offset/mask GEMM (B-frags on the fly from hsh)
    int mt = wv >> 1, nh = (wv & 1) * 3;
    int ocr = mt * 16 + lr;
    floatx4 oacc[3];
#pragma unroll
    for (int n = 0; n < 3; ++n) oacc[n] = (floatx4)0.f;
    int yn[3], xn[3];
#pragma unroll
    for (int ni = 0; ni < 3; ++ni) {
        int p = (nh + ni) * 16 + lr; p = p > 80 ? 80 : p;
        yn[ni] = p / 9; xn[ni] = p - 9 * yn[ni];
    }
#pragma unroll
    for (int s = 0; s < 18; ++s) {
        const int tap = s >> 1, dy = tap / 3 - 1, dx = tap % 3 - 1;
        const int cbb = ((s & 1) * 32 + lg * 8) * 4;     // byte base of 8 channels
        bfrag8 af = *(const bfrag8*)&wcm[(s * 32 + ocr) * 32 + lg * 8];
#pragma unroll
        for (int ni = 0; ni < 3; ++ni) {
            int yy = yn[ni] + dy, xx2 = xn[ni] + dx;
            bool val = ((unsigned)yy < 9u) & ((unsigned)xx2 < 9u);
            int q2 = val ? yy * 9 + xx2 : 0;
            const char* hr = (const char*)hsh + q2 * 256;
            int swz = (q2 & 31) << 3;
            float2 f0 = *(const float2*)(hr + ((cbb) ^ swz));
            float2 f1 = *(const float2*)(hr + ((cbb + 8) ^ swz));
            float2 f2 = *(const float2*)(hr + ((cbb + 16) ^ swz));
            float2 f3 = *(const float2*)(hr + ((cbb + 24) ^ swz));
            unsigned pk0, pk1, pk2, pk3;
            asm("v_cvt_pk_bf16_f32 %0, %1, %2" : "=v"(pk0) : "v"(f0.x), "v"(f0.y));
            asm("v_cvt_pk_bf16_f32 %0, %1, %2" : "=v"(pk1) : "v"(f1.x), "v"(f1.y));
            asm("v_cvt_pk_bf16_f32 %0, %1, %2" : "=v"(pk2) : "v"(f2.x), "v"(f2.y));
            asm("v_cvt_pk_bf16_f32 %0, %1, %2" : "=v"(pk3) : "v"(f3.x), "v"(f3.y));
            unsigned msk = val ? 0xffffffffu : 0u;
            unsigned r4[4] = { pk0 & msk, pk1 & msk, pk2 & msk, pk3 & msk };
            bfrag8 bf = *(bfrag8*)r4;
            oacc[ni] = __builtin_amdgcn_mfma_f32_16x16x32_bf16(af, bf, oacc[ni], 0, 0, 0);
        }
    }
    // P1 epilogue: offsets -> dout + LDS; mask -> LDS (sigmoid)
#pragma unroll
    for (int j = 0; j < 4; ++j) {
        int oc = mt * 16 + lg * 4 + j;
        if (oc < 18) {
            float bias = bo[oc];
            float* ob = dout + OUT_OFF_BASE + (size_t)b * 1458 + oc * 81;
#pragma unroll
            for (int ni = 0; ni < 3; ++ni) {
                int p = (nh + ni) * 16 + lr;
                if (p < 81) { float v = oacc[ni][j] + bias; ob[p] = v; om[oc * 81 + p] = v; }
            }
        } else if (oc < 27) {
            float bias = bm[oc - 18];
#pragma unroll
            for (int ni = 0; ni < 3; ++ni) {
                int p = (nh + ni) * 16 + lr;
                if (p < 81) { float v = oacc[ni][j] + bias; omm[(oc - 18) * 81 + p] = 1.f / (1.f + expf(-v)); }
            }
        }
    }
    __syncthreads();

    // ---- deform A fragments (issued here; L2-hot; latency hides under P2)
    int o = wv * 16 + lr;
    bfrag8 a[18];
#pragma unroll
    for (int s = 0; s < 18; ++s) {
        int k = s >> 1, ks = s & 1;
        a[s] = *(const bfrag8*)&wdt16[(k * 64 + o) * 64 + ks * 32 + lg * 8];
    }

    // ---- P2: bilinear params per (tap,pixel) from LDS offsets/mask
    for (int i = t; i < 729; i += 256) {
        int k = i / 81, p = i - k * 81;
        float dy = om[(2 * k) * 81 + p];
        float dx = om[(2 * k + 1) * 81 + p];
        float m  = omm[i];
        int y = p / 9, xx = p - y * 9;
        float py = dy + (float)(y + k / 3 - 1);
        float px = dx + (float)(xx + (k % 3) - 1);
        float fy = floorf(py), fx = floorf(px);
        float ly = py - fy, lx = px - fx;
        int y0 = (int)fy, x0 = (int)fx;
        int y1 = y0 + 1, x1 = x0 + 1;
        bool vy0 = (y0 >= 0) & (y0 < 9), vy1 = (y1 >= 0) & (y1 < 9);
        bool vx0 = (x0 >= 0) & (x0 < 9), vx1 = (x1 >= 0) & (x1 < 9);
        float w00 = (vy0 && vx0) ? m * (1.f - ly) * (1.f - lx) : 0.f;
        float w01 = (vy0 && vx1) ? m * (1.f - ly) * lx : 0.f;
        float w10 = (vy1 && vx0) ? m * ly * (1.f - lx) : 0.f;
        float w11 = (vy1 && vx1) ? m * ly * lx : 0.f;
        int yc0 = min(max(y0, 0), 8), yc1 = min(max(y1, 0), 8);
        int xc0 = min(max(x0, 0), 8), xc1 = min(max(x1, 0), 8);
        unsigned q00 = yc0 * 9 + xc0, q01 = yc0 * 9 + xc1;
        unsigned q10 = yc1 * 9 + xc0, q11 = yc1 * 9 + xc1;
        bwt[i] = make_uint2((unsigned)f2bf(w00) | ((unsigned)f2bf(w01) << 16),
                            (unsigned)f2bf(w10) | ((unsigned)f2bf(w11) << 16));
        bix[i] = q00 | (q01 << 8) | (q10 << 16) | (q11 << 24);
    }
    __syncthreads();   // om/omm dead; V region becomes vt

    // ---- fill tap kk into vt: 324 slots = (81 p) x (4 c-octets)
    auto stage_tap = [&](int kk) {
        int kbase = kk * 81;
        const char* hc = (const char*)hsh;
#pragma unroll
        for (int j = 0; j < 2; ++j) {
            int s = t + j * 256;
            if (j == 1 && s >= 324) break;
            int g = s & 3, p = s >> 2;
            uint2 bw = bwt[kbase + p];
            unsigned ix = bix[kbase + p];
            float w00 = bfhi2f(bw.x << 16), w01 = bfhi2f(bw.x & 0xffff0000u);
            float w10 = bfhi2f(bw.y << 16), w11 = bfhi2f(bw.y & 0xffff0000u);
            unsigned q00 = ix & 255u, q01 = (ix >> 8) & 255u;
            unsigned q10 = (ix >> 16) & 255u, q11 = ix >> 24;
            int b00 = (int)((q00 << 8) | ((q00 & 31u) << 3));
            int b01 = (int)((q01 << 8) | ((q01 & 31u) << 3));
            int b10 = (int)((q10 << 8) | ((q10 & 31u) << 3));
            int b11 = (int)((q11 << 8) | ((q11 & 31u) << 3));
            unsigned res[8];
#pragma unroll
            for (int i = 0; i < 8; ++i) {
                int c8 = (g * 8 + i) * 8;
                float2 v00 = *(const float2*)(hc + (b00 ^ c8));
                float2 v01 = *(const float2*)(hc + (b01 ^ c8));
                float2 v10 = *(const float2*)(hc + (b10 ^ c8));
                float2 v11 = *(const float2*)(hc + (b11 ^ c8));
                float s0 = w00 * v00.x + w01 * v01.x + w10 * v10.x + w11 * v11.x;
                float s1 = w00 * v00.y + w01 * v01.y + w10 * v10.y + w11 * v11.y;
                unsigned pk;
                asm("v_cvt_pk_bf16_f32 %0, %1, %2" : "=v"(pk) : "v"(s0), "v"(s1));
                res[i] = pk;
            }
            int swz = (p & 7) << 4;
            char* row = vtb + p * 128;
            *(uint4*)(row + ((32 * g) ^ swz)) = make_uint4(res[0], res[1], res[2], res[3]);
            *(uint4*)(row + ((32 * g + 16) ^ swz)) = make_uint4(res[4], res[5], res[6], res[7]);
        }
    };

    floatx4 acc[6];
#pragma unroll
    for (int n = 0; n < 6; ++n) acc[n] = (floatx4)0.f;
    int rowb[6], swzn[6];
#pragma unroll
    for (int n = 0; n < 6; ++n) {
        int row = n * 16 + lr; row = row > 80 ? 80 : row;
        rowb[n] = row * 128;
        swzn[n] = (row & 7) << 4;
    }

#pragma unroll
    for (int k = 0; k < 9; ++k) {
        stage_tap(k);
        __syncthreads();
        const char* vb = (const char*)vtb;
#pragma unroll
        for (int n = 0; n < 6; ++n) {
            bfrag8 b0 = *(const bfrag8*)(vb + rowb[n] + ((lg * 16) ^ swzn[n]));
            bfrag8 b1 = *(const bfrag8*)(vb + rowb[n] + ((64 + lg * 16) ^ swzn[n]));
            acc[n] = __builtin_amdgcn_mfma_f32_16x16x32_bf16(a[2 * k], b0, acc[n], 0, 0, 0);
            acc[n] = __builtin_amdgcn_mfma_f32_16x16x32_bf16(a[2 * k + 1], b1, acc[n], 0, 0, 0);
        }
        if (k < 8) __syncthreads();
    }

    // ---- epilogue: bias, pre-BN output, BN2 stats (replicated buckets)
    float* outb = dout + OUT_H_BASE + (size_t)b * 5184;
    int bucket = (b & 31) << 6;
#pragma unroll
    for (int j = 0; j < 4; ++j) {
        int oo = wv * 16 + lg * 4 + j;
        float bias = bd[oo];
        float ss = 0.f, qq = 0.f;
#pragma unroll
        for (int n = 0; n < 6; ++n) {
            int p = n * 16 + lr;
            float v = acc[n][j] + bias;
            if (p < 81) { outb[oo * 81 + p] = v; ss += v; qq += v * v; }
        }
#pragma unroll
        for (int off = 1; off < 16; off <<= 1) {
            ss += __shfl_xor(ss, off);
            qq += __shfl_xor(qq, off);
        }
        if (lr == 0) { atomicAdd(&sum2[bucket + oo], ss); atomicAdd(&sq2[bucket + oo], qq); }
    }
}

// ---------------- launch -------------------------------------------------------
extern "C" void kernel_launch(void* const* d_in, const int* in_sizes, int n_in,
                              void* d_out, int out_size, void* d_ws, size_t ws_size,
                              hipStream_t stream) {
    const float* x   = (const float*)d_in[0];
    const float* w1  = (const float*)d_in[1];
    const float* b1  = (const float*)d_in[2];
    const float* g1  = (const float*)d_in[3];
    const float* be1 = (const float*)d_in[4];
    const float* wo  = (const float*)d_in[5];
    const float* bo  = (const float*)d_in[6];
    const float* wm  = (const float*)d_in[7];
    const float* bm  = (const float*)d_in[8];
    const float* wd  = (const float*)d_in[9];
    const float* bd  = (const float*)d_in[10];
    const float* g2  = (const float*)d_in[11];
    const float* be2 = (const float*)d_in[12];
    float* dout = (float*)d_out;
    float* ws   = (float*)d_ws;

    float* h1    = ws + WS_H1;
    const unsigned short* wdt16 = (const unsigned short*)(ws + WS_WDT);
    const unsigned short* w1m   = (const unsigned short*)(ws + WS_W1M);
    const unsigned short* wcm   = (const unsigned short*)(ws + WS_WCM);
    float* stats = ws + WS_STATS;
    float* sum1 = stats,        *sq1 = stats + 2048;
    float* sum2 = stats + 4096, *sq2 = stats + 6144;
    float* scale1 = stats + 8192, *shift1 = stats + 8256;
    float* scale2 = stats + 8320, *shift2 = stats + 8384;

    // zero the replicated BN accumulators (ws is NOT re-poisoned between replays)
    hipMemsetAsync(stats, 0, 8192 * sizeof(float), stream);

    prep_weights<<<312, 256, 0, stream>>>(w1, wo, wm, wd, ws);
    conv1_mfma<<<BATCH, 256, 0, stream>>>(x, b1, w1m, h1, sum1, sq1);
    bn_finalize<<<1, 64, 0, stream>>>(sum1, sq1, g1, be1, scale1, shift1);
    offdeform_mfma<<<BATCH, 256, 0, stream>>>(h1, wcm, wdt16, bo, bm, bd,
                                              scale1, shift1, dout, sum2, sq2);
    bn_finalize<<<1, 64, 0, stream>>>(sum2, sq2, g2, be2, scale2, shift2);
    bn_apply<<<2048, 256, 0, stream>>>(dout + OUT_H_BASE, scale2, shift2, BATCH * 5184, 1, dout);
}

// Round 10
// 141.042 us; speedup vs baseline: 4.9284x; 1.0715x over previous
//
#include <hip/hip_runtime.h>
#include <hip/hip_bf16.h>

// Problem constants
#define BATCH   2048
#define HW      81          // 9x9
#define CIN     39
#define NPIX    (BATCH*HW)  // 165888

// ws layout (float offsets)
#define WS_H1     0              // 10,616,832 floats  (B,64,81)  PRE-BN h
#define WS_MASK   10616832       // 1,492,992 floats   (B,9,81)
#define WS_WDT    12109824       // 36,864 ushort bf16 [k][o][c]   (18,432 floats)
#define WS_W1M    12128256       // 24,576 ushort bf16 [12][64][32] (12,288 floats)
#define WS_WCM    12140544       // 18,432 ushort bf16 [18][32][32] (9,216 floats)
#define WS_STATS  12149760       // 8448 floats: sum1[2048],sq1[2048],sum2[2048],sq2[2048],
                                 //              scale1,shift1,scale2,shift2 (64 each)

#define OUT_OFF_BASE 1
#define OUT_H_BASE   (1 + BATCH*18*81)   // 2985985

typedef __attribute__((ext_vector_type(8))) short bfrag8;
typedef __attribute__((ext_vector_type(4))) float floatx4;

__device__ __forceinline__ unsigned short f2bf(float f) {
    unsigned u = __builtin_bit_cast(unsigned, f);
    u += 0x7FFFu + ((u >> 16) & 1u);       // round-to-nearest-even
    return (unsigned short)(u >> 16);
}
__device__ __forceinline__ float bfhi2f(unsigned hi16) {   // hi16 already in bits 31..16
    return __builtin_bit_cast(float, hi16);
}

// ---------------- weight prep: fragment-ready bf16 layouts --------------------
__global__ void prep_weights(const float* __restrict__ w1, const float* __restrict__ wo,
                             const float* __restrict__ wm, const float* __restrict__ wd,
                             float* __restrict__ ws) {
    int idx = blockIdx.x * 256 + threadIdx.x;
    unsigned short* w1m = (unsigned short*)(ws + WS_W1M);
    unsigned short* wcm = (unsigned short*)(ws + WS_WCM);
    unsigned short* wdt16 = (unsigned short*)(ws + WS_WDT);
    if (idx < 24576) {
        int kk = idx & 31, o = (idx >> 5) & 63, s = idx >> 11;
        int tap, c; bool ok = true;
        if (s < 9)       { tap = s;             c = kk; }
        else if (s == 9) { tap = kk >> 3;       c = 32 + (kk & 7); }
        else if (s == 10){ tap = 4 + (kk >> 3); c = 32 + (kk & 7); }
        else             { tap = 8;             c = 32 + (kk & 7); ok = (kk < 8); }
        float v = (ok && c < CIN) ? w1[(o * CIN + c) * 9 + tap] : 0.f;
        w1m[idx] = f2bf(v);
        return;
    }
    int j = idx - 24576;
    if (j >= 0 && j < 18432) {
        int kk = j & 31, oc = (j >> 5) & 31, s = j >> 10;
        int tap = s >> 1, c = (s & 1) * 32 + kk;
        float v = 0.f;
        if (oc < 18)      v = wo[(oc * 64 + c) * 9 + tap];
        else if (oc < 27) v = wm[((oc - 18) * 64 + c) * 9 + tap];
        wcm[j] = f2bf(v);
        return;
    }
    int m = idx - 24576 - 18432;
    if (m >= 0 && m < 36864) {
        int c = m & 63, o = (m >> 6) & 63, k = m >> 12;
        wdt16[m] = f2bf(wd[(o * 64 + c) * 9 + k]);
    }
}

// ---------------- conv1 (39->64) MFMA + ReLU + BN1 stats ----------------------
__global__ __launch_bounds__(256) void conv1_mfma(
        const float* __restrict__ xg, const float* __restrict__ b1,
        const unsigned short* __restrict__ w1m, float* __restrict__ h1,
        float* __restrict__ sum1, float* __restrict__ sq1) {
    __shared__ short xs[128 * 64];   // [r(121)][c(64)] bf16, byte ^= (r&7)<<4
    int b = blockIdx.x, t = threadIdx.x;
    for (int i = t; i < 4096; i += 256) ((unsigned*)xs)[i] = 0u;
    __syncthreads();
    const float* xb = xg + (size_t)b * (HW * CIN);
    for (int i = t; i < HW * CIN; i += 256) {
        int p = i / 39, c = i - 39 * p;
        int y = p / 9, xx = p - 9 * y;
        int r = (y + 1) * 11 + xx + 1;
        int byte = r * 128 + ((c * 2) ^ ((r & 7) << 4));
        xs[byte >> 1] = (short)f2bf(xb[i]);
    }
    __syncthreads();
    int lane = t & 63, wv = t >> 6, lg = lane >> 4, lr = lane & 15;
    int o = wv * 16 + lr;
    bfrag8 a[12];
#pragma unroll
    for (int s = 0; s < 12; ++s)
        a[s] = *(const bfrag8*)&w1m[(s * 64 + o) * 32 + lg * 8];
    floatx4 acc[6];
#pragma unroll
    for (int n = 0; n < 6; ++n) acc[n] = (floatx4)0.f;
#pragma unroll
    for (int n = 0; n < 6; ++n) {
        int p = n * 16 + lr; p = p > 80 ? 80 : p;
        int y = p / 9, xx = p - 9 * y;
        int rb = (y + 1) * 11 + xx + 1;
#pragma unroll
        for (int s = 0; s < 12; ++s) {
            int r, cb;
            if (s < 9)       { r = rb + (s / 3 - 1) * 11 + (s % 3) - 1; cb = lg * 16; }
            else if (s == 9) { r = rb + (lg / 3 - 1) * 11 + (lg % 3) - 1; cb = 64; }
            else if (s == 10){ int tp = lg + 4; r = rb + (tp / 3 - 1) * 11 + (tp % 3) - 1; cb = 64; }
            else             { r = rb + 12; cb = 64; }
            int byte = r * 128 + (cb ^ ((r & 7) << 4));
            bfrag8 bf = *(const bfrag8*)((const char*)xs + byte);
            acc[n] = __builtin_amdgcn_mfma_f32_16x16x32_bf16(a[s], bf, acc[n], 0, 0, 0);
        }
    }
    float* h1b = h1 + (size_t)b * 5184;
    int bucket = (b & 31) << 6;
#pragma unroll
    for (int j = 0; j < 4; ++j) {
        int oo = wv * 16 + lg * 4 + j;
        float bias = b1[oo];
        float ss = 0.f, qq = 0.f;
#pragma unroll
        for (int n = 0; n < 6; ++n) {
            int p = n * 16 + lr;
            float v = fmaxf(acc[n][j] + bias, 0.f);
            if (p < 81) { h1b[oo * 81 + p] = v; ss += v; qq += v * v; }
        }
#pragma unroll
        for (int off = 1; off < 16; off <<= 1) { ss += __shfl_xor(ss, off); qq += __shfl_xor(qq, off); }
        if (lr == 0) { atomicAdd(&sum1[bucket + oo], ss); atomicAdd(&sq1[bucket + oo], qq); }
    }
}

// ---------------- BN finalize (sums 32 replicated buckets) --------------------
__global__ void bn_finalize(const float* __restrict__ sums, const float* __restrict__ sqs,
                            const float* __restrict__ gamma, const float* __restrict__ beta,
                            float* __restrict__ scale, float* __restrict__ shift) {
    int t = threadIdx.x;   // 64
    float s = 0.f, q = 0.f;
#pragma unroll
    for (int r = 0; r < 32; ++r) { s += sums[(r << 6) + t]; q += sqs[(r << 6) + t]; }
    float m = s / (float)NPIX;
    float v = q / (float)NPIX - m * m;
    float sc = gamma[t] * (1.f / sqrtf(v + 1e-5f));
    scale[t] = sc;
    shift[t] = beta[t] - m * sc;
}

// ---------------- BN apply (final output) -------------------------------------
__global__ void bn_apply(float* __restrict__ data, const float* __restrict__ scale,
                         const float* __restrict__ shift, int n, int writeProb,
                         float* __restrict__ dout) {
    int i = blockIdx.x * blockDim.x + threadIdx.x;
    if (writeProb && i == 0) dout[0] = 0.5f;
    for (; i < n; i += gridDim.x * blockDim.x) {
        int c = (i / 81) & 63;
        data[i] = data[i] * scale[c] + shift[c];
    }
}

// ---------------- FUSED offset/mask conv + deformable conv (MFMA) --------------
// One block per image. LDS 39.9KB -> 4 blocks/CU:
//   hsh [0,20736)      f32 [q][256B], byte q*256 + ((c*4)^((q&15)<<4))  (16B-gran)
//   bwt [20736,26568)  uint2[729] packed bf16 bilinear weights
//   bix [26568,29484)  uint[729] 4x u8 corner q-indices
//   xs/vt [29488,39856) bf16 [r][64c], byte r*128 + ((c*2)^((r&7)<<4))
//     P0-P1: xs = post-BN bf16 image (P1 B-frags = single b128 read + zero-select)
//     fills: vt = per-tap V tile
// offsets/mask round-trip through global (dout / maskb) between P1 and P2.
__global__ __launch_bounds__(256, 4) void offdeform_mfma(
        const float* __restrict__ h1, const unsigned short* __restrict__ wcm,
        const unsigned short* __restrict__ wdt16,
        const float* __restrict__ bo, const float* __restrict__ bm,
        const float* __restrict__ bd,
        const float* __restrict__ scale1, const float* __restrict__ shift1,
        float* __restrict__ dout, float* __restrict__ maskb,
        float* __restrict__ sum2, float* __restrict__ sq2) {
    __shared__ __align__(16) char L[39856];
    float*    hsh = (float*)L;
    uint2*    bwt = (uint2*)(L + 20736);
    unsigned* bix = (unsigned*)(L + 26568);
    char*     vtb = L + 29488;               // xs during P0/P1, vt during fills

    int b = blockIdx.x, t = threadIdx.x;
    int lane = t & 63, wv = t >> 6, lg = lane >> 4, lr = lane & 15;

    // ---- P0: stage h as f32 hsh (swizzled) + bf16 xs (vt layout), BN1 folded
    const float* hb = h1 + (size_t)b * 5184;
    for (int i = t; i < 2592; i += 256) {
        int c2 = i / 81, q = i - c2 * 81;
        int c = 2 * c2;
        float va = hb[c * 81 + q]      * scale1[c]     + shift1[c];
        float vb = hb[c * 81 + 81 + q] * scale1[c + 1] + shift1[c + 1];
        *(float2*)((char*)hsh + q * 256 + ((c * 4) ^ ((q & 15) << 4))) = make_float2(va, vb);
        unsigned pk;
        asm("v_cvt_pk_bf16_f32 %0, %1, %2" : "=v"(pk) : "v"(va), "v"(vb));
        *(unsigned*)(vtb + q * 128 + ((c * 2) ^ ((q & 7) << 4))) = pk;
    }
    __syncthreads();

    // ---- P1: offset/mask GEMM; B-frags = single b128 read from xs + zero-select
    int mt = wv >> 1, nh = (wv & 1) * 3;
    int ocr = mt * 16 + lr;
    floatx4 oacc[3];
#pragma unroll
    for (int n = 0; n < 3; ++n) oacc[n] = (floatx4)0.f;
    int yn[3], xn[3];
#pragma unroll
    for (int ni = 0; ni < 3; ++ni) {
        int p = (nh + ni) * 16 + lr; p = p > 80 ? 80 : p;
        yn[ni] = p / 9; xn[ni] = p - 9 * yn[ni];
    }
#pragma unroll
    for (int s = 0; s < 18; ++s) {
        const int tap = s >> 1, dyk = tap / 3 - 1, dxk = tap % 3 - 1;
        const int cb1 = (s & 1) * 64 + lg * 16;     // byte base in xs row
        bfrag8 af = *(const bfrag8*)&wcm[(s * 32 + ocr) * 32 + lg * 8];
#pragma unroll
        for (int ni = 0; ni < 3; ++ni) {
            int yy = yn[ni] + dyk, xx2 = xn[ni] + dxk;
            bool val = ((unsigned)yy < 9u) & ((unsigned)xx2 < 9u);
            int q2 = val ? yy * 9 + xx2 : 0;
            bfrag8 bf = *(const bfrag8*)(vtb + q2 * 128 + (cb1 ^ ((q2 & 7) << 4)));
            bf = val ? bf : (bfrag8)0;
            oacc[ni] = __builtin_amdgcn_mfma_f32_16x16x32_bf16(af, bf, oacc[ni], 0, 0, 0);
        }
    }
    // P1 epilogue: offsets -> dout (program output), mask -> maskb (global)
#pragma unroll
    for (int j = 0; j < 4; ++j) {
        int oc = mt * 16 + lg * 4 + j;
        if (oc < 18) {
            float bias = bo[oc];
            float* ob = dout + OUT_OFF_BASE + (size_t)b * 1458 + oc * 81;
#pragma unroll
            for (int ni = 0; ni < 3; ++ni) {
                int p = (nh + ni) * 16 + lr;
                if (p < 81) ob[p] = oacc[ni][j] + bias;
            }
        } else if (oc < 27) {
            float bias = bm[oc - 18];
            float* mb = maskb + (size_t)b * 729 + (oc - 18) * 81;
#pragma unroll
            for (int ni = 0; ni < 3; ++ni) {
                int p = (nh + ni) * 16 + lr;
                if (p < 81) { float v = oacc[ni][j] + bias; mb[p] = 1.f / (1.f + expf(-v)); }
            }
        }
    }
    __syncthreads();   // xs reads done; stores drained (vmcnt(0) before barrier)

    // ---- deform A fragments (L2-hot; latency hides under P2)
    int o = wv * 16 + lr;
    bfrag8 a[18];
#pragma unroll
    for (int s = 0; s < 18; ++s) {
        int k = s >> 1, ks = s & 1;
        a[s] = *(const bfrag8*)&wdt16[(k * 64 + o) * 64 + ks * 32 + lg * 8];
    }

    // ---- P2: bilinear params per (tap,pixel) from global offsets/mask
    const float* goff = dout + OUT_OFF_BASE + (size_t)b * 1458;
    const float* gmsk = maskb + (size_t)b * 729;
    for (int i = t; i < 729; i += 256) {
        int k = i / 81, p = i - k * 81;
        float dy = goff[(2 * k) * 81 + p];
        float dx = goff[(2 * k + 1) * 81 + p];
        float m  = gmsk[i];
        int y = p / 9, xx = p - y * 9;
        float py = dy + (float)(y + k / 3 - 1);
        float px = dx + (float)(xx + (k % 3) - 1);
        float fy = floorf(py), fx = floorf(px);
        float ly = py - fy, lx = px - fx;
        int y0 = (int)fy, x0 = (int)fx;
        int y1 = y0 + 1, x1 = x0 + 1;
        bool vy0 = (y0 >= 0) & (y0 < 9), vy1 = (y1 >= 0) & (y1 < 9);
        bool vx0 = (x0 >= 0) & (x0 < 9), vx1 = (x1 >= 0) & (x1 < 9);
        float w00 = (vy0 && vx0) ? m * (1.f - ly) * (1.f - lx) : 0.f;
        float w01 = (vy0 && vx1) ? m * (1.f - ly) * lx : 0.f;
        float w10 = (vy1 && vx0) ? m * ly * (1.f - lx) : 0.f;
        float w11 = (vy1 && vx1) ? m * ly * lx : 0.f;
        int yc0 = min(max(y0, 0), 8), yc1 = min(max(y1, 0), 8);
        int xc0 = min(max(x0, 0), 8), xc1 = min(max(x1, 0), 8);
        unsigned q00 = yc0 * 9 + xc0, q01 = yc0 * 9 + xc1;
        unsigned q10 = yc1 * 9 + xc0, q11 = yc1 * 9 + xc1;
        bwt[i] = make_uint2((unsigned)f2bf(w00) | ((unsigned)f2bf(w01) << 16),
                            (unsigned)f2bf(w10) | ((unsigned)f2bf(w11) << 16));
        bix[i] = q00 | (q01 << 8) | (q10 << 16) | (q11 << 24);
    }
    __syncthreads();   // xs dead; vt region free for fills; bwt/bix visible

    // ---- fill tap kk into vt: 324 slots = (81 p) x (4 c-octets), b128 reads
    auto stage_tap = [&](int kk) {
        int kbase = kk * 81;
        const char* hc = (const char*)hsh;
#pragma unroll
        for (int j2 = 0; j2 < 2; ++j2) {
            int s = t + j2 * 256;
            if (j2 == 1 && s >= 324) break;
            int g = s & 3, p = s >> 2;
            uint2 bw = bwt[kbase + p];
            unsigned ix = bix[kbase + p];
            float w00 = bfhi2f(bw.x << 16), w01 = bfhi2f(bw.x & 0xffff0000u);
            float w10 = bfhi2f(bw.y << 16), w11 = bfhi2f(bw.y & 0xffff0000u);
            unsigned q00 = ix & 255u, q01 = (ix >> 8) & 255u;
            unsigned q10 = (ix >> 16) & 255u, q11 = ix >> 24;
            int b00 = (int)((q00 << 8) | ((q00 & 15u) << 4));
            int b01 = (int)((q01 << 8) | ((q01 & 15u) << 4));
            int b10 = (int)((q10 << 8) | ((q10 & 15u) << 4));
            int b11 = (int)((q11 << 8) | ((q11 & 15u) << 4));
            int gb = g * 64;
            unsigned res[8];
#pragma unroll
            for (int jj = 0; jj < 4; ++jj) {
                int off = gb + jj * 16;
                floatx4 a4 = *(const floatx4*)(hc + (b00 ^ off)) * w00;
                a4 += *(const floatx4*)(hc + (b01 ^ off)) * w01;
                a4 += *(const floatx4*)(hc + (b10 ^ off)) * w10;
                a4 += *(const floatx4*)(hc + (b11 ^ off)) * w11;
                unsigned pk0, pk1;
                asm("v_cvt_pk_bf16_f32 %0, %1, %2" : "=v"(pk0) : "v"(a4.x), "v"(a4.y));
                asm("v_cvt_pk_bf16_f32 %0, %1, %2" : "=v"(pk1) : "v"(a4.z), "v"(a4.w));
                res[2 * jj] = pk0; res[2 * jj + 1] = pk1;
            }
            int swzv = (p & 7) << 4;
            char* row = vtb + p * 128;
            *(uint4*)(row + ((32 * g) ^ swzv)) = make_uint4(res[0], res[1], res[2], res[3]);
            *(uint4*)(row + ((32 * g + 16) ^ swzv)) = make_uint4(res[4], res[5], res[6], res[7]);
        }
    };

    floatx4 acc[6];
#pragma unroll
    for (int n = 0; n < 6; ++n) acc[n] = (floatx4)0.f;
    int rowb[6], swzn[6];
#pragma unroll
    for (int n = 0; n < 6; ++n) {
        int row = n * 16 + lr; row = row > 80 ? 80 : row;
        rowb[n] = row * 128;
        swzn[n] = (row & 7) << 4;
    }

#pragma unroll
    for (int k = 0; k < 9; ++k) {
        stage_tap(k);
        __syncthreads();
        const char* vb = (const char*)vtb;
#pragma unroll
        for (int n = 0; n < 6; ++n) {
            bfrag8 b0 = *(const bfrag8*)(vb + rowb[n] + ((lg * 16) ^ swzn[n]));
            bfrag8 b1 = *(const bfrag8*)(vb + rowb[n] + ((64 + lg * 16) ^ swzn[n]));
            acc[n] = __builtin_amdgcn_mfma_f32_16x16x32_bf16(a[2 * k], b0, acc[n], 0, 0, 0);
            acc[n] = __builtin_amdgcn_mfma_f32_16x16x32_bf16(a[2 * k + 1], b1, acc[n], 0, 0, 0);
        }
        if (k < 8) __syncthreads();
    }

    // ---- epilogue: bias, pre-BN output, BN2 stats (replicated buckets)
    float* outb = dout + OUT_H_BASE + (size_t)b * 5184;
    int bucket = (b & 31) << 6;
#pragma unroll
    for (int j = 0; j < 4; ++j) {
        int oo = wv * 16 + lg * 4 + j;
        float bias = bd[oo];
        float ss = 0.f, qq = 0.f;
#pragma unroll
        for (int n = 0; n < 6; ++n) {
            int p = n * 16 + lr;
            float v = acc[n][j] + bias;
            if (p < 81) { outb[oo * 81 + p] = v; ss += v; qq += v * v; }
        }
#pragma unroll
        for (int off = 1; off < 16; off <<= 1) {
            ss += __shfl_xor(ss, off);
            qq += __shfl_xor(qq, off);
        }
        if (lr == 0) { atomicAdd(&sum2[bucket + oo], ss); atomicAdd(&sq2[bucket + oo], qq); }
    }
}

// ---------------- launch -------------------------------------------------------
extern "C" void kernel_launch(void* const* d_in, const int* in_sizes, int n_in,
                              void* d_out, int out_size, void* d_ws, size_t ws_size,
                              hipStream_t stream) {
    const float* x   = (const float*)d_in[0];
    const float* w1  = (const float*)d_in[1];
    const float* b1  = (const float*)d_in[2];
    const float* g1  = (const float*)d_in[3];
    const float* be1 = (const float*)d_in[4];
    const float* wo  = (const float*)d_in[5];
    const float* bo  = (const float*)d_in[6];
    const float* wm  = (const float*)d_in[7];
    const float* bm  = (const float*)d_in[8];
    const float* wd  = (const float*)d_in[9];
    const float* bd  = (const float*)d_in[10];
    const float* g2  = (const float*)d_in[11];
    const float* be2 = (const float*)d_in[12];
    float* dout = (float*)d_out;
    float* ws   = (float*)d_ws;

    float* h1    = ws + WS_H1;
    float* maskb = ws + WS_MASK;
    const unsigned short* wdt16 = (const unsigned short*)(ws + WS_WDT);
    const unsigned short* w1m   = (const unsigned short*)(ws + WS_W1M);
    const unsigned short* wcm   = (const unsigned short*)(ws + WS_WCM);
    float* stats = ws + WS_STATS;
    float* sum1 = stats,        *sq1 = stats + 2048;
    float* sum2 = stats + 4096, *sq2 = stats + 6144;
    float* scale1 = stats + 8192, *shift1 = stats + 8256;
    float* scale2 = stats + 8320, *shift2 = stats + 8384;

    // zero the replicated BN accumulators (ws is NOT re-poisoned between replays)
    hipMemsetAsync(stats, 0, 8192 * sizeof(float), stream);

    prep_weights<<<312, 256, 0, stream>>>(w1, wo, wm, wd, ws);
    conv1_mfma<<<BATCH, 256, 0, stream>>>(x, b1, w1m, h1, sum1, sq1);
    bn_finalize<<<1, 64, 0, stream>>>(sum1, sq1, g1, be1, scale1, shift1);
    offdeform_mfma<<<BATCH, 256, 0, stream>>>(h1, wcm, wdt16, bo, bm, bd,
                                              scale1, shift1, dout, maskb, sum2, sq2);
    bn_finalize<<<1, 64, 0, stream>>>(sum2, sq2, g2, be2, scale2, shift2);
    bn_apply<<<2048, 256, 0, stream>>>(dout + OUT_H_BASE, scale2, shift2, BATCH * 5184, 1, dout);
}

// Round 12
// 133.539 us; speedup vs baseline: 5.2053x; 1.0562x over previous
//
#include <hip/hip_runtime.h>
#include <hip/hip_bf16.h>

// Problem constants
#define BATCH   2048
#define HW      81          // 9x9
#define CIN     39
#define NPIX    (BATCH*HW)  // 165888

// ws layout (float offsets)
#define WS_H1     0              // 10,616,832 floats  (B,64,81)  PRE-BN h
#define WS_MASK   10616832       // 1,492,992 floats   (B,9,81)
#define WS_WDT    12109824       // 36,864 ushort bf16 [k][o][c]   (18,432 floats)
#define WS_W1M    12128256       // 24,576 ushort bf16 [12][64][32] (12,288 floats)
#define WS_WCM    12140544       // 18,432 ushort bf16 [18][32][32] (9,216 floats)
#define WS_STATS  12149760       // 8192 floats: sum1[2048],sq1[2048],sum2[2048],sq2[2048]

#define OUT_OFF_BASE 1
#define OUT_H_BASE   (1 + BATCH*18*81)   // 2985985

typedef __attribute__((ext_vector_type(8))) short bfrag8;
typedef __attribute__((ext_vector_type(4))) float floatx4;

__device__ __forceinline__ unsigned short f2bf(float f) {
    unsigned u = __builtin_bit_cast(unsigned, f);
    u += 0x7FFFu + ((u >> 16) & 1u);       // round-to-nearest-even
    return (unsigned short)(u >> 16);
}
__device__ __forceinline__ float bfhi2f(unsigned hi16) {   // hi16 already in bits 31..16
    return __builtin_bit_cast(float, hi16);
}

// ---------------- weight prep: fragment-ready bf16 layouts --------------------
__global__ void prep_weights(const float* __restrict__ w1, const float* __restrict__ wo,
                             const float* __restrict__ wm, const float* __restrict__ wd,
                             float* __restrict__ ws) {
    int idx = blockIdx.x * 256 + threadIdx.x;
    unsigned short* w1m = (unsigned short*)(ws + WS_W1M);
    unsigned short* wcm = (unsigned short*)(ws + WS_WCM);
    unsigned short* wdt16 = (unsigned short*)(ws + WS_WDT);
    if (idx < 24576) {
        int kk = idx & 31, o = (idx >> 5) & 63, s = idx >> 11;
        int tap, c; bool ok = true;
        if (s < 9)       { tap = s;             c = kk; }
        else if (s == 9) { tap = kk >> 3;       c = 32 + (kk & 7); }
        else if (s == 10){ tap = 4 + (kk >> 3); c = 32 + (kk & 7); }
        else             { tap = 8;             c = 32 + (kk & 7); ok = (kk < 8); }
        float v = (ok && c < CIN) ? w1[(o * CIN + c) * 9 + tap] : 0.f;
        w1m[idx] = f2bf(v);
        return;
    }
    int j = idx - 24576;
    if (j >= 0 && j < 18432) {
        int kk = j & 31, oc = (j >> 5) & 31, s = j >> 10;
        int tap = s >> 1, c = (s & 1) * 32 + kk;
        float v = 0.f;
        if (oc < 18)      v = wo[(oc * 64 + c) * 9 + tap];
        else if (oc < 27) v = wm[((oc - 18) * 64 + c) * 9 + tap];
        wcm[j] = f2bf(v);
        return;
    }
    int m = idx - 24576 - 18432;
    if (m >= 0 && m < 36864) {
        int c = m & 63, o = (m >> 6) & 63, k = m >> 12;
        wdt16[m] = f2bf(wd[(o * 64 + c) * 9 + k]);
    }
}

// ---------------- conv1 (39->64) MFMA + ReLU + BN1 stats ----------------------
// float4 staging; s-outer loop (one A-frag live); VGPR capped for 4 waves/SIMD.
__global__ __launch_bounds__(256, 4) void conv1_mfma(
        const float* __restrict__ xg, const float* __restrict__ b1,
        const unsigned short* __restrict__ w1m, float* __restrict__ h1,
        float* __restrict__ sum1, float* __restrict__ sq1) {
    __shared__ short xs[128 * 64];   // [r(121)][c(64)] bf16, byte ^= (r&7)<<4
    int b = blockIdx.x, t = threadIdx.x;
    for (int i = t; i < 4096; i += 256) ((unsigned*)xs)[i] = 0u;
    __syncthreads();
    const float* xb = xg + (size_t)b * (HW * CIN);
    const float4* xb4 = (const float4*)xb;
    for (int i4 = t; i4 < 789; i4 += 256) {
        float4 v = xb4[i4];
        float vv[4] = { v.x, v.y, v.z, v.w };
        int base = 4 * i4;
#pragma unroll
        for (int k = 0; k < 4; ++k) {
            int idx = base + k;
            int p = idx / 39, c = idx - 39 * p;
            int y = p / 9, xx = p - 9 * y;
            int r = (y + 1) * 11 + xx + 1;
            int byte = r * 128 + ((c * 2) ^ ((r & 7) << 4));
            xs[byte >> 1] = (short)f2bf(vv[k]);
        }
    }
    if (t < 3) {
        int idx = 3156 + t;
        int p = idx / 39, c = idx - 39 * p;
        int y = p / 9, xx = p - 9 * y;
        int r = (y + 1) * 11 + xx + 1;
        int byte = r * 128 + ((c * 2) ^ ((r & 7) << 4));
        xs[byte >> 1] = (short)f2bf(xb[idx]);
    }
    __syncthreads();
    int lane = t & 63, wv = t >> 6, lg = lane >> 4, lr = lane & 15;
    int o = wv * 16 + lr;
    floatx4 acc[6];
#pragma unroll
    for (int n = 0; n < 6; ++n) acc[n] = (floatx4)0.f;
    int rbn[6];
#pragma unroll
    for (int n = 0; n < 6; ++n) {
        int p = n * 16 + lr; p = p > 80 ? 80 : p;
        int y = p / 9, xx = p - 9 * y;
        rbn[n] = (y + 1) * 11 + xx + 1;
    }
#pragma unroll
    for (int s = 0; s < 12; ++s) {
        bfrag8 a = *(const bfrag8*)&w1m[(s * 64 + o) * 32 + lg * 8];
        int roff, cb;
        if (s < 9)       { roff = (s / 3 - 1) * 11 + (s % 3) - 1; cb = lg * 16; }
        else if (s == 9) { roff = (lg / 3 - 1) * 11 + (lg % 3) - 1; cb = 64; }
        else if (s == 10){ int tp = lg + 4; roff = (tp / 3 - 1) * 11 + (tp % 3) - 1; cb = 64; }
        else             { roff = 12; cb = 64; }
#pragma unroll
        for (int n = 0; n < 6; ++n) {
            int r = rbn[n] + roff;
            int byte = r * 128 + (cb ^ ((r & 7) << 4));
            bfrag8 bf = *(const bfrag8*)((const char*)xs + byte);
            acc[n] = __builtin_amdgcn_mfma_f32_16x16x32_bf16(a, bf, acc[n], 0, 0, 0);
        }
    }
    float* h1b = h1 + (size_t)b * 5184;
    int bucket = (b & 31) << 6;
#pragma unroll
    for (int j = 0; j < 4; ++j) {
        int oo = wv * 16 + lg * 4 + j;
        float bias = b1[oo];
        float ss = 0.f, qq = 0.f;
#pragma unroll
        for (int n = 0; n < 6; ++n) {
            int p = n * 16 + lr;
            float v = fmaxf(acc[n][j] + bias, 0.f);
            if (p < 81) { h1b[oo * 81 + p] = v; ss += v; qq += v * v; }
        }
#pragma unroll
        for (int off = 1; off < 16; off <<= 1) { ss += __shfl_xor(ss, off); qq += __shfl_xor(qq, off); }
        if (lr == 0) { atomicAdd(&sum1[bucket + oo], ss); atomicAdd(&sq1[bucket + oo], qq); }
    }
}

// ---------------- BN2 finalize + apply (fused; aligned float4 body) -----------
// data = dout + OUT_H_BASE is only 4B-aligned; elements 0..2 scalar head,
// float4 body from element 3 (16B-aligned), scalar tail element n-1.
__global__ __launch_bounds__(256) void bn_apply2(
        float* __restrict__ data, const float* __restrict__ sums,
        const float* __restrict__ sqs, const float* __restrict__ gamma,
        const float* __restrict__ beta, int n, float* __restrict__ dout) {
    __shared__ float sc[64], sh[64];
    int t = threadIdx.x;
    if (t < 64) {
        float s = 0.f, q = 0.f;
#pragma unroll
        for (int r = 0; r < 32; ++r) { s += sums[(r << 6) + t]; q += sqs[(r << 6) + t]; }
        float m = s / (float)NPIX;
        float v = q / (float)NPIX - m * m;
        float scv = gamma[t] * (1.f / sqrtf(v + 1e-5f));
        sc[t] = scv; sh[t] = beta[t] - m * scv;
    }
    __syncthreads();
    if (blockIdx.x == 0) {
        if (t == 0) dout[0] = 0.5f;
        if (t < 3) data[t] = data[t] * sc[0] + sh[0];   // e<81 -> c=0
        if (t == 3) {
            int e = n - 1;
            int c = (e / 81) & 63;
            data[e] = data[e] * sc[c] + sh[c];
        }
    }
    float4* d4 = (float4*)(data + 3);
    int n4 = (n - 4) >> 2;    // covers elements 3 .. n-2
    for (int i = blockIdx.x * 256 + t; i < n4; i += gridDim.x * 256) {
        float4 v = d4[i];
        unsigned e = 3u + 4u * (unsigned)i;
        int c0 = (int)((e) / 81u) & 63;
        int c1 = (int)((e + 1) / 81u) & 63;
        int c2 = (int)((e + 2) / 81u) & 63;
        int c3 = (int)((e + 3) / 81u) & 63;
        v.x = v.x * sc[c0] + sh[c0];
        v.y = v.y * sc[c1] + sh[c1];
        v.z = v.z * sc[c2] + sh[c2];
        v.w = v.w * sc[c3] + sh[c3];
        d4[i] = v;
    }
}

// ---------------- FUSED offset/mask conv + deformable conv (MFMA) --------------
// Round-10 proven structure (offsets/mask round-trip via global; direct bwt/bix
// writes) + exonerated round-11 wins: BN1 finalize folded in, zero-row OOB
// fragments, float-free P1 B-frags from the bf16 xs image. No setprio.
// LDS 40496B -> 4 blocks/CU:
//   hsh [0,20736)      f32 [q][256B], byte q*256 + ((c*4)^((q&15)<<4))
//   bwt [20736,26568)  uint2[729] packed bf16 bilinear weights
//   bix [26568,29484)  uint[729] 4x u8 corner q-indices
//   xs/vt [29488,39984) bf16 [r(82)][64c], byte r*128 + ((c*2)^((r&7)<<4));
//                       row 81 = zeros (P1 OOB fragments)
//   sc1/sh1 [39984,40496) BN1 scale/shift
__global__ __launch_bounds__(256, 4) void offdeform_mfma(
        const float* __restrict__ h1, const unsigned short* __restrict__ wcm,
        const unsigned short* __restrict__ wdt16,
        const float* __restrict__ bo, const float* __restrict__ bm,
        const float* __restrict__ bd,
        const float* __restrict__ sum1, const float* __restrict__ sq1,
        const float* __restrict__ g1, const float* __restrict__ be1,
        float* __restrict__ dout, float* __restrict__ maskb,
        float* __restrict__ sum2, float* __restrict__ sq2) {
    __shared__ __align__(16) char L[40496];
    float*    hsh = (float*)L;
    uint2*    bwt = (uint2*)(L + 20736);
    unsigned* bix = (unsigned*)(L + 26568);
    char*     vtb = L + 29488;               // xs during P0/P1, vt during fills
    float*    sc1 = (float*)(L + 39984);
    float*    sh1 = (float*)(L + 40240);

    int b = blockIdx.x, t = threadIdx.x;
    int lane = t & 63, wv = t >> 6, lg = lane >> 4, lr = lane & 15;

    // ---- BN1 finalize folded in (per block, cheap)
    if (t < 64) {
        float s = 0.f, q = 0.f;
#pragma unroll
        for (int r = 0; r < 32; ++r) { s += sum1[(r << 6) + t]; q += sq1[(r << 6) + t]; }
        float m = s / (float)NPIX;
        float v = q / (float)NPIX - m * m;
        float scv = g1[t] * (1.f / sqrtf(v + 1e-5f));
        sc1[t] = scv; sh1[t] = be1[t] - m * scv;
    }
    __syncthreads();

    // ---- P0: stage h as f32 hsh (swizzled) + bf16 xs (vt layout), BN1 folded
    const float* hb = h1 + (size_t)b * 5184;
    for (int i = t; i < 2592; i += 256) {
        int c2 = i / 81, q = i - c2 * 81;
        int c = 2 * c2;
        float va = hb[c * 81 + q]      * sc1[c]     + sh1[c];
        float vb = hb[c * 81 + 81 + q] * sc1[c + 1] + sh1[c + 1];
        *(float2*)((char*)hsh + q * 256 + ((c * 4) ^ ((q & 15) << 4))) = make_float2(va, vb);
        unsigned pk;
        asm("v_cvt_pk_bf16_f32 %0, %1, %2" : "=v"(pk) : "v"(va), "v"(vb));
        *(unsigned*)(vtb + q * 128 + ((c * 2) ^ ((q & 7) << 4))) = pk;
    }
    if (t < 32) *(unsigned*)(vtb + 81 * 128 + t * 4) = 0u;   // zero row 81
    __syncthreads();

    // ---- P1: offset/mask GEMM; OOB fragments -> zero row (no select)
    int mt = wv >> 1, nh = (wv & 1) * 3;
    int ocr = mt * 16 + lr;
    floatx4 oacc[3];
#pragma unroll
    for (int n = 0; n < 3; ++n) oacc[n] = (floatx4)0.f;
    int yn[3], xn[3];
#pragma unroll
    for (int ni = 0; ni < 3; ++ni) {
        int p = (nh + ni) * 16 + lr; p = p > 80 ? 80 : p;
        yn[ni] = p / 9; xn[ni] = p - 9 * yn[ni];
    }
#pragma unroll
    for (int s = 0; s < 18; ++s) {
        const int tap = s >> 1, dyk = tap / 3 - 1, dxk = tap % 3 - 1;
        const int cb1 = (s & 1) * 64 + lg * 16;
        bfrag8 af = *(const bfrag8*)&wcm[(s * 32 + ocr) * 32 + lg * 8];
#pragma unroll
        for (int ni = 0; ni < 3; ++ni) {
            int yy = yn[ni] + dyk, xx2 = xn[ni] + dxk;
            bool val = ((unsigned)yy < 9u) & ((unsigned)xx2 < 9u);
            int q2 = val ? yy * 9 + xx2 : 81;
            bfrag8 bf = *(const bfrag8*)(vtb + q2 * 128 + (cb1 ^ ((q2 & 7) << 4)));
            oacc[ni] = __builtin_amdgcn_mfma_f32_16x16x32_bf16(af, bf, oacc[ni], 0, 0, 0);
        }
    }
    // P1 epilogue: offsets -> dout (program output), mask -> maskb (global)
#pragma unroll
    for (int j = 0; j < 4; ++j) {
        int oc = mt * 16 + lg * 4 + j;
        if (oc < 18) {
            float bias = bo[oc];
            float* ob = dout + OUT_OFF_BASE + (size_t)b * 1458 + oc * 81;
#pragma unroll
            for (int ni = 0; ni < 3; ++ni) {
                int p = (nh + ni) * 16 + lr;
                if (p < 81) ob[p] = oacc[ni][j] + bias;
            }
        } else if (oc < 27) {
            float bias = bm[oc - 18];
            float* mb = maskb + (size_t)b * 729 + (oc - 18) * 81;
#pragma unroll
            for (int ni = 0; ni < 3; ++ni) {
                int p = (nh + ni) * 16 + lr;
                if (p < 81) { float v = oacc[ni][j] + bias; mb[p] = 1.f / (1.f + expf(-v)); }
            }
        }
    }
    __syncthreads();   // xs reads done; stores drained (vmcnt(0) before barrier)

    // ---- deform A fragments (L2-hot; latency hides under P2)
    int o = wv * 16 + lr;
    bfrag8 a[18];
#pragma unroll
    for (int s = 0; s < 18; ++s) {
        int k = s >> 1, ks = s & 1;
        a[s] = *(const bfrag8*)&wdt16[(k * 64 + o) * 64 + ks * 32 + lg * 8];
    }

    // ---- P2: bilinear params per (tap,pixel) from global offsets/mask
    const float* goff = dout + OUT_OFF_BASE + (size_t)b * 1458;
    const float* gmsk = maskb + (size_t)b * 729;
    for (int i = t; i < 729; i += 256) {
        int k = i / 81, p = i - k * 81;
        float dy = goff[(2 * k) * 81 + p];
        float dx = goff[(2 * k + 1) * 81 + p];
        float m  = gmsk[i];
        int y = p / 9, xx = p - y * 9;
        float py = dy + (float)(y + k / 3 - 1);
        float px = dx + (float)(xx + (k % 3) - 1);
        float fy = floorf(py), fx = floorf(px);
        float ly = py - fy, lx = px - fx;
        int y0 = (int)fy, x0 = (int)fx;
        int y1 = y0 + 1, x1 = x0 + 1;
        bool vy0 = (y0 >= 0) & (y0 < 9), vy1 = (y1 >= 0) & (y1 < 9);
        bool vx0 = (x0 >= 0) & (x0 < 9), vx1 = (x1 >= 0) & (x1 < 9);
        float w00 = (vy0 && vx0) ? m * (1.f - ly) * (1.f - lx) : 0.f;
        float w01 = (vy0 && vx1) ? m * (1.f - ly) * lx : 0.f;
        float w10 = (vy1 && vx0) ? m * ly * (1.f - lx) : 0.f;
        float w11 = (vy1 && vx1) ? m * ly * lx : 0.f;
        int yc0 = min(max(y0, 0), 8), yc1 = min(max(y1, 0), 8);
        int xc0 = min(max(x0, 0), 8), xc1 = min(max(x1, 0), 8);
        unsigned q00 = yc0 * 9 + xc0, q01 = yc0 * 9 + xc1;
        unsigned q10 = yc1 * 9 + xc0, q11 = yc1 * 9 + xc1;
        bwt[i] = make_uint2((unsigned)f2bf(w00) | ((unsigned)f2bf(w01) << 16),
                            (unsigned)f2bf(w10) | ((unsigned)f2bf(w11) << 16));
        bix[i] = q00 | (q01 << 8) | (q10 << 16) | (q11 << 24);
    }
    __syncthreads();   // xs dead; vt region free for fills; bwt/bix visible

    // ---- fill tap kk into vt: 324 slots = (81 p) x (4 c-octets), b128 reads
    auto stage_tap = [&](int kk) {
        int kbase = kk * 81;
        const char* hc = (const char*)hsh;
#pragma unroll
        for (int j2 = 0; j2 < 2; ++j2) {
            int s = t + j2 * 256;
            if (j2 == 1 && s >= 324) break;
            int g = s & 3, p = s >> 2;
            uint2 bw = bwt[kbase + p];
            unsigned ix = bix[kbase + p];
            float w00 = bfhi2f(bw.x << 16), w01 = bfhi2f(bw.x & 0xffff0000u);
            float w10 = bfhi2f(bw.y << 16), w11 = bfhi2f(bw.y & 0xffff0000u);
            unsigned q00 = ix & 255u, q01 = (ix >> 8) & 255u;
            unsigned q10 = (ix >> 16) & 255u, q11 = ix >> 24;
            int b00 = (int)((q00 << 8) | ((q00 & 15u) << 4));
            int b01 = (int)((q01 << 8) | ((q01 & 15u) << 4));
            int b10 = (int)((q10 << 8) | ((q10 & 15u) << 4));
            int b11 = (int)((q11 << 8) | ((q11 & 15u) << 4));
            int gb = g * 64;
            unsigned res[8];
#pragma unroll
            for (int jj = 0; jj < 4; ++jj) {
                int off = gb + jj * 16;
                floatx4 a4 = *(const floatx4*)(hc + (b00 ^ off)) * w00;
                a4 += *(const floatx4*)(hc + (b01 ^ off)) * w01;
                a4 += *(const floatx4*)(hc + (b10 ^ off)) * w10;
                a4 += *(const floatx4*)(hc + (b11 ^ off)) * w11;
                unsigned pk0, pk1;
                asm("v_cvt_pk_bf16_f32 %0, %1, %2" : "=v"(pk0) : "v"(a4.x), "v"(a4.y));
                asm("v_cvt_pk_bf16_f32 %0, %1, %2" : "=v"(pk1) : "v"(a4.z), "v"(a4.w));
                res[2 * jj] = pk0; res[2 * jj + 1] = pk1;
            }
            int swzv = (p & 7) << 4;
            char* row = vtb + p * 128;
            *(uint4*)(row + ((32 * g) ^ swzv)) = make_uint4(res[0], res[1], res[2], res[3]);
            *(uint4*)(row + ((32 * g + 16) ^ swzv)) = make_uint4(res[4], res[5], res[6], res[7]);
        }
    };

    floatx4 acc[6];
#pragma unroll
    for (int n = 0; n < 6; ++n) acc[n] = (floatx4)0.f;
    int rowb[6], swzn[6];
#pragma unroll
    for (int n = 0; n < 6; ++n) {
        int row = n * 16 + lr; row = row > 80 ? 80 : row;
        rowb[n] = row * 128;
        swzn[n] = (row & 7) << 4;
    }

#pragma unroll
    for (int k = 0; k < 9; ++k) {
        stage_tap(k);
        __syncthreads();
        const char* vb = (const char*)vtb;
#pragma unroll
        for (int n = 0; n < 6; ++n) {
            bfrag8 b0 = *(const bfrag8*)(vb + rowb[n] + ((lg * 16) ^ swzn[n]));
            bfrag8 b1 = *(const bfrag8*)(vb + rowb[n] + ((64 + lg * 16) ^ swzn[n]));
            acc[n] = __builtin_amdgcn_mfma_f32_16x16x32_bf16(a[2 * k], b0, acc[n], 0, 0, 0);
            acc[n] = __builtin_amdgcn_mfma_f32_16x16x32_bf16(a[2 * k + 1], b1, acc[n], 0, 0, 0);
        }
        if (k < 8) __syncthreads();
    }

    // ---- epilogue: bias, pre-BN output, BN2 stats (replicated buckets)
    float* outb = dout + OUT_H_BASE + (size_t)b * 5184;
    int bucket = (b & 31) << 6;
#pragma unroll
    for (int j = 0; j < 4; ++j) {
        int oo = wv * 16 + lg * 4 + j;
        float bias = bd[oo];
        float ss = 0.f, qq = 0.f;
#pragma unroll
        for (int n = 0; n < 6; ++n) {
            int p = n * 16 + lr;
            float v = acc[n][j] + bias;
            if (p < 81) { outb[oo * 81 + p] = v; ss += v; qq += v * v; }
        }
#pragma unroll
        for (int off = 1; off < 16; off <<= 1) {
            ss += __shfl_xor(ss, off);
            qq += __shfl_xor(qq, off);
        }
        if (lr == 0) { atomicAdd(&sum2[bucket + oo], ss); atomicAdd(&sq2[bucket + oo], qq); }
    }
}

// ---------------- launch -------------------------------------------------------
extern "C" void kernel_launch(void* const* d_in, const int* in_sizes, int n_in,
                              void* d_out, int out_size, void* d_ws, size_t ws_size,
                              hipStream_t stream) {
    const float* x   = (const float*)d_in[0];
    const float* w1  = (const float*)d_in[1];
    const float* b1  = (const float*)d_in[2];
    const float* g1  = (const float*)d_in[3];
    const float* be1 = (const float*)d_in[4];
    const float* wo  = (const float*)d_in[5];
    const float* bo  = (const float*)d_in[6];
    const float* wm  = (const float*)d_in[7];
    const float* bm  = (const float*)d_in[8];
    const float* wd  = (const float*)d_in[9];
    const float* bd  = (const float*)d_in[10];
    const float* g2  = (const float*)d_in[11];
    const float* be2 = (const float*)d_in[12];
    float* dout = (float*)d_out;
    float* ws   = (float*)d_ws;

    float* h1    = ws + WS_H1;
    float* maskb = ws + WS_MASK;
    const unsigned short* wdt16 = (const unsigned short*)(ws + WS_WDT);
    const unsigned short* w1m   = (const unsigned short*)(ws + WS_W1M);
    const unsigned short* wcm   = (const unsigned short*)(ws + WS_WCM);
    float* stats = ws + WS_STATS;
    float* sum1 = stats,        *sq1 = stats + 2048;
    float* sum2 = stats + 4096, *sq2 = stats + 6144;

    // zero the replicated BN accumulators (ws is NOT re-poisoned between replays)
    hipMemsetAsync(stats, 0, 8192 * sizeof(float), stream);

    prep_weights<<<312, 256, 0, stream>>>(w1, wo, wm, wd, ws);
    conv1_mfma<<<BATCH, 256, 0, stream>>>(x, b1, w1m, h1, sum1, sq1);
    offdeform_mfma<<<BATCH, 256, 0, stream>>>(h1, wcm, wdt16, bo, bm, bd,
                                              sum1, sq1, g1, be1, dout, maskb, sum2, sq2);
    bn_apply2<<<2048, 256, 0, stream>>>(dout + OUT_H_BASE, sum2, sq2, g2, be2,
                                        BATCH * 5184, dout);
}